// Round 9
// baseline (481.643 us; speedup 1.0000x reference)
//
#include <hip/hip_runtime.h>
#include <hip/hip_cooperative_groups.h>
namespace cg = cooperative_groups;

#define N_NODES 50000
#define N_EDGES 800000
#define FEATS 128
#define NCHUNK 196            // ceil(50000/256)
#define CPAD 50176            // NCHUNK*256 (loc padded)
#define GEMM_BX 196
#define GEMM_BLOCKS 392       // 196 qv-merged + 196 k
#define CSR_BLOCKS 1024       // cooperative: colscan/fold phase + scatter phase
#define NTILE 782             // ceil(50000/64)
#define NF_WAVES 8192
#define STAT_BLOCKS 512
#define HIST_BLOCKS 512       // 128 segments x 4 quarter-ranges
#define HSEG 128
#define ESEG 6250
#define HQ 12544              // bins per quarter (4*12544 = 50176 = CPAD)
#define CPQ 49                // chunks per quarter (12544/256)

typedef __attribute__((ext_vector_type(8))) short bf16x8;
typedef __attribute__((ext_vector_type(4))) float f32x4;
typedef union { uint4 u; bf16x8 v; } pack8;

__device__ __forceinline__ unsigned short f2bf(float f){
  unsigned u = __float_as_uint(f);
  u += 0x7FFF + ((u >> 16) & 1);           // RNE
  return (unsigned short)(u >> 16);
}
// HW packed f32->bf16 (RNE), 2 values / inst
__device__ __forceinline__ unsigned cvtpk(float lo, float hi){
  unsigned r;
  asm("v_cvt_pk_bf16_f32 %0, %1, %2" : "=v"(r) : "v"(lo), "v"(hi));
  return r;
}
// bf16 pair unpack, 1 VALU op per float
__device__ __forceinline__ void unpack8(uint4 p, float* f){
  f[0]=__uint_as_float(p.x << 16); f[1]=__uint_as_float(p.x & 0xffff0000u);
  f[2]=__uint_as_float(p.y << 16); f[3]=__uint_as_float(p.y & 0xffff0000u);
  f[4]=__uint_as_float(p.z << 16); f[5]=__uint_as_float(p.z & 0xffff0000u);
  f[6]=__uint_as_float(p.w << 16); f[7]=__uint_as_float(p.w & 0xffff0000u);
}

// ---------------- node 1: BN stats + bf16 q-emit (0..511) || quarter-hist + rank + ctot (512..1023)
__global__ __launch_bounds__(256) void stats_hist_kernel(
    const float* __restrict__ ftq, const float* __restrict__ ftk,
    float* __restrict__ sums, unsigned short* __restrict__ xqb,
    const int* __restrict__ dstE, unsigned short* __restrict__ rankE,
    unsigned short* __restrict__ hmat, unsigned short* __restrict__ ctot){
  __shared__ float red[4*FEATS];               // 2 KB
  __shared__ unsigned lh[HQ/2];                // 12544 u16 bins packed -> 25088 B
  int tid = threadIdx.x, bid = blockIdx.x;
  if (bid < STAT_BLOCKS){
    for (int i = tid; i < 4*FEATS; i += 256) red[i] = 0.f;
    __syncthreads();
    int sub = tid >> 5, c4 = tid & 31;         // 32 lanes cover one 128-f row
    const float* Xs = (sub < 4) ? ftq : ftk;
    int so = (sub < 4) ? 0 : 2*FEATS;
    bool isq = (sub < 4);
    float a0=0,a1=0,a2=0,a3=0,b0=0,b1=0,b2=0,b3=0;
    #pragma unroll 4
    for (int r = bid*4 + (sub&3); r < N_NODES; r += STAT_BLOCKS*4){
      float4 x = *(const float4*)(Xs + (size_t)r*FEATS + c4*4);
      if (isq)  // bf16 A rows for qv GEMM plane (same RNE as GEMM-side cvt)
        *(uint2*)&xqb[(size_t)r*FEATS + c4*4] = make_uint2(cvtpk(x.x,x.y), cvtpk(x.z,x.w));
      a0+=x.x; b0+=x.x*x.x; a1+=x.y; b1+=x.y*x.y;
      a2+=x.z; b2+=x.z*x.z; a3+=x.w; b3+=x.w*x.w;
    }
    a0 += __shfl_xor(a0,32); a1 += __shfl_xor(a1,32);
    a2 += __shfl_xor(a2,32); a3 += __shfl_xor(a3,32);
    b0 += __shfl_xor(b0,32); b1 += __shfl_xor(b1,32);
    b2 += __shfl_xor(b2,32); b3 += __shfl_xor(b3,32);
    if ((tid & 63) < 32){
      int c0 = c4*4;
      atomicAdd(&red[so + c0+0], a0); atomicAdd(&red[so + c0+1], a1);
      atomicAdd(&red[so + c0+2], a2); atomicAdd(&red[so + c0+3], a3);
      atomicAdd(&red[so + FEATS + c0+0], b0); atomicAdd(&red[so + FEATS + c0+1], b1);
      atomicAdd(&red[so + FEATS + c0+2], b2); atomicAdd(&red[so + FEATS + c0+3], b3);
    }
    __syncthreads();
    for (int i = tid; i < 4*FEATS; i += 256) atomicAdd(&sums[i], red[i]);
  } else {
    int hb = bid - STAT_BLOCKS;                // 0..511
    int seg = hb >> 2, q = hb & 3;
    int dlo = q * HQ;
    for (int i = tid; i < HQ/2; i += 256) lh[i] = 0;
    __syncthreads();
    int e0 = seg * ESEG;
    for (int t = e0 + tid; t < e0 + ESEG; t += 256){
      int d = dstE[t] - dlo;
      if ((unsigned)d < (unsigned)HQ){
        unsigned sh = (d & 1) * 16;
        unsigned old = atomicAdd(&lh[d >> 1], 1u << sh);
        rankE[t] = (unsigned short)((old >> sh) & 0xffffu);   // local rank in (seg,d)
      }
    }
    __syncthreads();
    unsigned* row = (unsigned*)(hmat + (size_t)hb * HQ);
    for (int i = tid; i < HQ/2; i += 256) row[i] = lh[i];
    // per-chunk totals -> ctot (plain stores, no atomics)
    int wv = tid >> 6, ln = tid & 63;
    for (int c = wv; c < CPQ; c += 4){
      unsigned w0 = lh[c*128 + ln];
      unsigned w1 = lh[c*128 + 64 + ln];
      unsigned t = (w0 & 0xffffu) + (w0 >> 16) + (w1 & 0xffffu) + (w1 >> 16);
      #pragma unroll
      for (int o = 1; o < 64; o <<= 1) t += __shfl_xor((int)t, o);
      if (ln == 0) ctot[hb*CPQ + c] = (unsigned short)t;   // total <= 6250 fits u16
    }
  }
}

// ---------------- node 2 (cooperative): phase1 = colscan(0..195) || fold(196..291) || bscan(292)
//                                        grid.sync -> phase2 = atomic-free CSR scatter (grid-stride)
__global__ __launch_bounds__(256) void csr_build_kernel(
    const unsigned short* __restrict__ hmat, unsigned short* __restrict__ hbase,
    int* __restrict__ loc, const unsigned short* __restrict__ ctot, int* __restrict__ bscan,
    const float* __restrict__ Wq, const float* __restrict__ bq,
    const float* __restrict__ Wk, const float* __restrict__ Wv,
    const float* __restrict__ gq, const float* __restrict__ bqn,
    const float* __restrict__ gk, const float* __restrict__ bkn,
    const float* __restrict__ sums,
    unsigned short* __restrict__ Wb, float* __restrict__ bias,
    const int* __restrict__ dstE, const int* __restrict__ srcE,
    const unsigned short* __restrict__ rankE, int* __restrict__ src_csr){
  __shared__ int s[256];
  int tid = threadIdx.x, bid = blockIdx.x;
  if (bid < NCHUNK){
    int q = bid / CPQ;                         // chunks never straddle quarters (49*256=12544)
    int d = bid*256 + tid;
    int col = d - q*HQ;
    const unsigned short* hp = hmat + (size_t)q*HQ + col;   // row hb = seg*4+q
    unsigned short* bp = hbase + (size_t)q*HQ + col;
    int run = 0;
    #pragma unroll 8
    for (int sg = 0; sg < HSEG; sg++){
      int v = hp[(size_t)sg*4*HQ];
      bp[(size_t)sg*4*HQ] = (unsigned short)run;   // exclusive prefix over segments
      run += v;
    }
    s[tid] = run; __syncthreads();
    for (int dd = 1; dd < 256; dd <<= 1){
      int tv = (tid >= dd) ? s[tid-dd] : 0; __syncthreads();
      s[tid] += tv; __syncthreads();
    }
    loc[d] = s[tid] - run;                     // chunk-local exclusive
  } else if (bid < NCHUNK + 96){               // BN-fold roles
    int wv = (bid - NCHUNK)*4 + (tid >> 6);    // 0..383
    int lane = tid & 63;
    int m = wv >> 7;                           // 0=q,1=v,2=k
    int o = wv & 127;
    const float* Wsrc = (m==0) ? Wq : (m==1) ? Wv : Wk;
    const float* g   = (m==2) ? gk : gq;
    const float* bb  = (m==2) ? bkn : bqn;
    const float* s0  = (m==2) ? (sums + 2*FEATS) : sums;
    const float invN = 1.0f / (float)N_NODES;
    float acc = 0.f;
    unsigned short w2[2];
    int i0 = lane*2;
    #pragma unroll
    for (int t = 0; t < 2; t++){
      int i = i0 + t;
      float mean = s0[i]*invN;
      float var  = s0[FEATS+i]*invN - mean*mean;
      float rstd = rsqrtf(var + 1e-5f);
      float scale = g[i]*rstd;
      float shift = bb[i] - mean*scale;
      float w = Wsrc[o*FEATS + i];
      w2[t] = f2bf(w*scale);
      acc += shift*w;
    }
    ((unsigned*)Wb)[(m*FEATS*FEATS + o*FEATS + i0) >> 1] =
        (unsigned)w2[0] | ((unsigned)w2[1] << 16);
    #pragma unroll
    for (int off = 1; off < 64; off <<= 1) acc += __shfl_xor(acc, off);
    if (lane == 0) bias[m*FEATS + o] = acc + ((m==0) ? bq[o] : 0.f);
  } else if (bid == NCHUNK + 96){              // bscan role: reduce ctot, ladder-scan
    int v = 0;
    if (tid < NCHUNK){
      int q = tid / CPQ, cc = tid - q*CPQ;
      const unsigned short* cp = ctot + q*CPQ + cc;   // row hb = seg*4+q
      #pragma unroll 8
      for (int sg = 0; sg < HSEG; sg++) v += cp[(size_t)sg*4*CPQ];
    }
    s[tid] = v; __syncthreads();
    for (int dd = 1; dd < 256; dd <<= 1){
      int tv = (tid >= dd) ? s[tid-dd] : 0; __syncthreads();
      s[tid] += tv; __syncthreads();
    }
    if (tid < NCHUNK) bscan[tid] = s[tid] - v;
  }
  __threadfence();
  cg::this_grid().sync();
  // phase 2: scatter (grid-stride over edges; thin, no LDS pressure)
  for (int t = bid*256 + tid; t < N_EDGES; t += CSR_BLOCKS*256){
    int d = dstE[t];
    int seg = t / ESEG;
    int q = d / HQ;
    int base = (int)hbase[(size_t)(seg*4 + q)*HQ + (d - q*HQ)];
    src_csr[loc[d] + bscan[d >> 8] + base + (int)rankE[t]] = srcE[t];
  }
}

// ---------------- node 3: merged-plane GEMM
// blocks 0..195:  A=xqb (bf16, no convert), B = {Wq, Wv} both staged -> q and v outputs
// blocks 196..391: A=ftk (f32 + cvtpk),     B = {Wk}                 -> k output
__global__ __launch_bounds__(256) void gemm_kernel(
    const unsigned short* __restrict__ xqb, const float* __restrict__ ftk,
    const unsigned short* __restrict__ Wball, const float* __restrict__ biasall,
    unsigned short* __restrict__ qv, unsigned short* __restrict__ kb){
  __shared__ unsigned short Bs[2][FEATS][FEATS];   // 64KB, XOR-swizzled 16B chunks
  int tid = threadIdx.x, bid = blockIdx.x;
  int isk = (bid >= GEMM_BX);
  int bx = isk ? bid - GEMM_BX : bid;
  int nplanes = isk ? 1 : 2;
  { // stage B plane(s) with chunk-XOR swizzle: chunk' = chunk ^ (row&15)
    for (int p = 0; p < nplanes; p++){
      int m = isk ? 2 : p;
      const uint4* srcp = (const uint4*)(Wball + m*FEATS*FEATS);
      for (int idx = tid; idx < FEATS*FEATS/8; idx += 256){
        int n = idx >> 4, ck = idx & 15;
        *(uint4*)&Bs[p][n][(ck ^ (n & 15))*8] = srcp[idx];
      }
    }
  }
  __syncthreads();                              // only barrier in the kernel
  int wave = tid >> 6, lane = tid & 63;
  int mrow = lane & 15, quad = lane >> 4;
  float bv[2][8];
  #pragma unroll
  for (int p = 0; p < 2; p++)
    #pragma unroll
    for (int ct = 0; ct < 8; ct++)
      bv[p][ct] = biasall[(isk ? 2 : p)*FEATS + ct*16 + mrow];
  uint4 cur[4], nxt[4];
  auto loadA = [&](uint4* buf, int t){
    int arow = t*64 + wave*16 + mrow;
    if (!isk){
      const unsigned short* xp = xqb + (size_t)arow*FEATS + quad*8;  // padded rows
      buf[0] = *(const uint4*)xp;
      buf[1] = *(const uint4*)(xp + 32);
      buf[2] = *(const uint4*)(xp + 64);
      buf[3] = *(const uint4*)(xp + 96);
    } else {
      bool rok = arow < N_NODES;
      const float* xp = ftk + (size_t)(rok ? arow : 0)*FEATS + quad*8;
      #pragma unroll
      for (int kt = 0; kt < 4; kt++){
        float4 x0 = *(const float4*)(xp + kt*32);
        float4 x1 = *(const float4*)(xp + kt*32 + 4);
        if (!rok){ x0 = make_float4(0.f,0.f,0.f,0.f); x1 = x0; }
        buf[kt].x = cvtpk(x0.x, x0.y); buf[kt].y = cvtpk(x0.z, x0.w);
        buf[kt].z = cvtpk(x1.x, x1.y); buf[kt].w = cvtpk(x1.z, x1.w);
      }
    }
  };
  loadA(cur, bx);
  for (int t = bx; t < NTILE; t += GEMM_BX){
    int tn = t + GEMM_BX;
    if (tn < NTILE) loadA(nxt, tn);             // prefetch next A tile under MFMA
    f32x4 acc[2][8];
    #pragma unroll
    for (int p = 0; p < 2; p++)
      #pragma unroll
      for (int i = 0; i < 8; i++) acc[p][i] = (f32x4){0.f,0.f,0.f,0.f};
    #pragma unroll
    for (int kt = 0; kt < 4; kt++){
      pack8 a; a.u = cur[kt];
      #pragma unroll
      for (int ct = 0; ct < 8; ct++){
        bf16x8 b0 = *(bf16x8*)&Bs[0][ct*16 + mrow][((kt*4 + quad) ^ mrow)*8];
        acc[0][ct] = __builtin_amdgcn_mfma_f32_16x16x32_bf16(a.v, b0, acc[0][ct], 0, 0, 0);
      }
      if (!isk){
        #pragma unroll
        for (int ct = 0; ct < 8; ct++){
          bf16x8 b1 = *(bf16x8*)&Bs[1][ct*16 + mrow][((kt*4 + quad) ^ mrow)*8];
          acc[1][ct] = __builtin_amdgcn_mfma_f32_16x16x32_bf16(a.v, b1, acc[1][ct], 0, 0, 0);
        }
      }
    }
    int row0 = t*64;
    #pragma unroll
    for (int p = 0; p < 2; p++){
      if (isk && p) break;
      unsigned short* Out = isk ? kb : (qv + p*128);
      const int ostride = isk ? FEATS : 256;
      #pragma unroll
      for (int ct = 0; ct < 8; ct++){
        int col = ct*16 + mrow;
        #pragma unroll
        for (int v = 0; v < 4; v++){
          int orow = row0 + wave*16 + quad*4 + v;
          float sv = acc[p][ct][v] + bv[p][ct];
          float pf = __shfl_xor(sv, 1);         // partner col's f32 sum
          if (!(mrow & 1) && orow < N_NODES)
            *(unsigned*)&Out[(size_t)orow*ostride + col] = cvtpk(sv, pf);
        }
      }
    }
    #pragma unroll
    for (int i = 0; i < 4; i++) cur[i] = nxt[i];
  }
}

// ---------------- node 4: per-dst-node scores + max-free softmax agg (static interleave)
__global__ __launch_bounds__(256) void node_fused_kernel(
    const unsigned short* __restrict__ qv, const unsigned short* __restrict__ kb,
    const float* __restrict__ attn, const int* __restrict__ src_csr,
    const int* __restrict__ loc, const int* __restrict__ bscan,
    float* __restrict__ out){
  int tid = threadIdx.x;
  int lane = tid & 63;
  int h = lane & 7, g = lane >> 3;
  int w = blockIdx.x*4 + (tid >> 6);
  const float L2E = 1.44269504f;
  float ar[16];
  {
    const uint4* ap = (const uint4*)(attn + h*16);
    uint4 a0 = ap[0], a1 = ap[1], a2 = ap[2], a3 = ap[3];
    ar[0]=__uint_as_float(a0.x); ar[1]=__uint_as_float(a0.y); ar[2]=__uint_as_float(a0.z); ar[3]=__uint_as_float(a0.w);
    ar[4]=__uint_as_float(a1.x); ar[5]=__uint_as_float(a1.y); ar[6]=__uint_as_float(a1.z); ar[7]=__uint_as_float(a1.w);
    ar[8]=__uint_as_float(a2.x); ar[9]=__uint_as_float(a2.y); ar[10]=__uint_as_float(a2.z); ar[11]=__uint_as_float(a2.w);
    ar[12]=__uint_as_float(a3.x); ar[13]=__uint_as_float(a3.y); ar[14]=__uint_as_float(a3.z); ar[15]=__uint_as_float(a3.w);
  }
  for (int n = w; n < N_NODES; n += NF_WAVES){
    int off0 = loc[n]   + bscan[n>>8];
    int off1 = loc[n+1] + bscan[(n+1)>>8];      // loc[50000] valid (padded chunk 195)
    int deg = off1 - off0;
    if (deg == 0){
      ((float2*)(out + (size_t)n*FEATS))[lane] = make_float2(0.f, 0.f);
      continue;
    }
    float kf2[16];
    {
      const unsigned short* kr = kb + (size_t)n*FEATS + h*16;
      uint4 k0 = *(const uint4*)kr;
      uint4 k1 = *(const uint4*)(kr + 8);
      float kf[16]; unpack8(k0, kf); unpack8(k1, kf+8);
      #pragma unroll
      for (int i = 0; i < 16; i++) kf2[i] = -L2E * kf[i];
    }
    float ssum = 0.f;
    float acc[16];
    #pragma unroll
    for (int i = 0; i < 16; i++) acc[i] = 0.f;
    if (g < deg){
      int sA = src_csr[off0 + g];
      int jB = g + 8;
      int sB = (jB < deg) ? src_csr[off0 + jB] : sA;   // dup tail -> L1 hit
      const unsigned short* pA = qv + (size_t)sA*256 + h*16;
      uint4 qa0 = *(const uint4*)pA;
      uint4 qa1 = *(const uint4*)(pA + 8);
      while (true){
        uint4 va0 = *(const uint4*)(pA + 128);   // current v (interleaved row)
        uint4 va1 = *(const uint4*)(pA + 136);
        const unsigned short* pB = qv + (size_t)sB*256 + h*16;
        uint4 qb0 = *(const uint4*)pB;           // next q prefetch
        uint4 qb1 = *(const uint4*)(pB + 8);
        int jC = jB + 8;
        int sC = (jC < deg) ? src_csr[off0 + jC] : sB;
        float qf[16]; unpack8(qa0, qf); unpack8(qa1, qf+8);
        float ta = 0.f, tb = 0.f, tc = 0.f, td = 0.f;
        #pragma unroll
        for (int i = 0; i < 16; i += 4){
          float x0 = fmaf(qf[i+0], -L2E, kf2[i+0]);
          float x1 = fmaf(qf[i+1], -L2E, kf2[i+1]);
          float x2 = fmaf(qf[i+2], -L2E, kf2[i+2]);
          float x3 = fmaf(qf[i+3], -L2E, kf2[i+3]);
          ta = fmaf(ar[i+0], __builtin_amdgcn_rcpf(1.f + __builtin_amdgcn_exp2f(x0)), ta);
          tb = fmaf(ar[i+1], __builtin_amdgcn_rcpf(1.f + __builtin_amdgcn_exp2f(x1)), tb);
          tc = fmaf(ar[i+2], __builtin_amdgcn_rcpf(1.f + __builtin_amdgcn_exp2f(x2)), tc);
          td = fmaf(ar[i+3], __builtin_amdgcn_rcpf(1.f + __builtin_amdgcn_exp2f(x3)), td);
        }
        float t = (ta + tb) + (tc + td);
        float ex = __builtin_amdgcn_exp2f(t * L2E);   // |t|<=sum|attn| -> max-free safe
        ssum += ex;
        float vf[16]; unpack8(va0, vf); unpack8(va1, vf+8);
        #pragma unroll
        for (int i = 0; i < 16; i++) acc[i] = fmaf(ex, vf[i], acc[i]);
        if (jB >= deg) break;
        qa0 = qb0; qa1 = qb1; pA = pB;
        jB = jC; sB = sC;
      }
    }
    ssum += __shfl_xor(ssum, 8); ssum += __shfl_xor(ssum, 16); ssum += __shfl_xor(ssum, 32);
    #pragma unroll
    for (int i = 0; i < 16; i++){
      acc[i] += __shfl_xor(acc[i], 8);
      acc[i] += __shfl_xor(acc[i], 16);
      acc[i] += __shfl_xor(acc[i], 32);
    }
    if (g == 0){
      float inv_s = 1.f / ssum;
      float4* op = (float4*)(out + (size_t)n*FEATS + h*16);
      op[0] = make_float4(acc[0]*inv_s, acc[1]*inv_s, acc[2]*inv_s, acc[3]*inv_s);
      op[1] = make_float4(acc[4]*inv_s, acc[5]*inv_s, acc[6]*inv_s, acc[7]*inv_s);
      op[2] = make_float4(acc[8]*inv_s, acc[9]*inv_s, acc[10]*inv_s, acc[11]*inv_s);
      op[3] = make_float4(acc[12]*inv_s, acc[13]*inv_s, acc[14]*inv_s, acc[15]*inv_s);
    }
  }
}

extern "C" void kernel_launch(void* const* d_in, const int* in_sizes, int n_in,
                              void* d_out, int out_size, void* d_ws, size_t ws_size,
                              hipStream_t stream){
  (void)in_sizes; (void)n_in; (void)out_size; (void)ws_size;
  const float* ftq  = (const float*)d_in[0];
  const float* ftk  = (const float*)d_in[1];
  const int*   srcE = (const int*)d_in[2];
  const int*   dstE = (const int*)d_in[3];
  const float* Wq   = (const float*)d_in[4];
  const float* bq   = (const float*)d_in[5];
  const float* Wk   = (const float*)d_in[6];
  const float* Wv   = (const float*)d_in[7];
  const float* attn = (const float*)d_in[8];
  const float* gq   = (const float*)d_in[9];
  const float* bqn  = (const float*)d_in[10];
  const float* gk   = (const float*)d_in[11];
  const float* bkn  = (const float*)d_in[12];

  char* ws = (char*)d_ws;
  float* sums    = (float*)(ws + 0);             // 512 f     [0, 2048)  <- only memset
  int*   bscan   = (int*)(ws + 2048);            // 196 i     -> 2832
  int*   loc     = (int*)(ws + 4096);            // CPAD i    -> 204800
  int*   src_csr = (int*)(ws + 204800);          // 800000 i  -> 3404800
  unsigned short* rankE = (unsigned short*)(ws + 3404800);   // 800000 u16 -> 5004800
  unsigned short* hmat  = (unsigned short*)(ws + 5004800);   // 512*12544 u16 -> 17849856
  unsigned short* hbase = (unsigned short*)(ws + 17849856);  // 512*12544 u16 -> 30694912
  unsigned short* ctot  = (unsigned short*)(ws + 30694912);  // 512*49 u16 -> 30745088
  unsigned short* Wb    = (unsigned short*)(ws + 30745088);  // 3*16384 u16 -> 30843392
  float* biasf   = (float*)(ws + 30843392);      // 384 f -> 30844928
  unsigned short* xqb = (unsigned short*)(ws + 30844928);    // 50176*128 u16 -> 43689984
  unsigned short* qv  = (unsigned short*)(ws + 43689984);    // 50000*256 u16 -> 69289984
  unsigned short* kb  = (unsigned short*)(ws + 69289984);    // 50000*128 u16 -> 82089984
  float* out = (float*)d_out;

  hipMemsetAsync(ws, 0, 2048, stream);  // sums only

  hipLaunchKernelGGL(stats_hist_kernel, dim3(STAT_BLOCKS + HIST_BLOCKS), dim3(256), 0, stream,
                     ftq, ftk, sums, xqb, dstE, rankE, hmat, ctot);
  {
    void* args[] = { (void*)&hmat, (void*)&hbase, (void*)&loc, (void*)&ctot, (void*)&bscan,
                     (void*)&Wq, (void*)&bq, (void*)&Wk, (void*)&Wv,
                     (void*)&gq, (void*)&bqn, (void*)&gk, (void*)&bkn,
                     (void*)&sums, (void*)&Wb, (void*)&biasf,
                     (void*)&dstE, (void*)&srcE, (void*)&rankE, (void*)&src_csr };
    hipLaunchCooperativeKernel((const void*)csr_build_kernel, dim3(CSR_BLOCKS), dim3(256),
                               args, 0, stream);
  }
  hipLaunchKernelGGL(gemm_kernel, dim3(GEMM_BLOCKS), dim3(256), 0, stream,
                     xqb, ftk, Wb, biasf, qv, kb);
  hipLaunchKernelGGL(node_fused_kernel, dim3(NF_WAVES/4), dim3(256), 0, stream,
                     qv, kb, attn, src_csr, loc, bscan, out);
}

// Round 10
// 275.634 us; speedup vs baseline: 1.7474x; 1.7474x over previous
//
#include <hip/hip_runtime.h>

#define N_NODES 50000
#define N_EDGES 800000
#define FEATS 128
#define NCHUNK 196            // ceil(50000/256)
#define CPAD 50176            // NCHUNK*256 (loc padded)
#define GEMM_BX 196
#define GEMM_BLOCKS 392       // 196 qv-merged + 196 k
#define SCAT_BLOCKS 3125      // 3125*256 = 800000 exactly
#define NTILE 782             // ceil(50000/64)
#define NF_WAVES 8192
#define STAT_BLOCKS 512
#define HIST_BLOCKS 512       // 128 segments x 4 quarter-ranges
#define HSEG 128
#define ESEG 6250
#define HQ 12544              // bins per quarter (4*12544 = 50176 = CPAD)
#define CPQ 49                // chunks per quarter (12544/256)

typedef __attribute__((ext_vector_type(8))) short bf16x8;
typedef __attribute__((ext_vector_type(4))) float f32x4;
typedef union { uint4 u; bf16x8 v; } pack8;

__device__ __forceinline__ unsigned short f2bf(float f){
  unsigned u = __float_as_uint(f);
  u += 0x7FFF + ((u >> 16) & 1);           // RNE
  return (unsigned short)(u >> 16);
}
// HW packed f32->bf16 (RNE), 2 values / inst
__device__ __forceinline__ unsigned cvtpk(float lo, float hi){
  unsigned r;
  asm("v_cvt_pk_bf16_f32 %0, %1, %2" : "=v"(r) : "v"(lo), "v"(hi));
  return r;
}
// bf16 pair unpack, 1 VALU op per float
__device__ __forceinline__ void unpack8(uint4 p, float* f){
  f[0]=__uint_as_float(p.x << 16); f[1]=__uint_as_float(p.x & 0xffff0000u);
  f[2]=__uint_as_float(p.y << 16); f[3]=__uint_as_float(p.y & 0xffff0000u);
  f[4]=__uint_as_float(p.z << 16); f[5]=__uint_as_float(p.z & 0xffff0000u);
  f[6]=__uint_as_float(p.w << 16); f[7]=__uint_as_float(p.w & 0xffff0000u);
}

// ---------------- node 1: BN stats + bf16 q/k-emit (0..511) || quarter-hist + rank + ctot (512..1023)
__global__ __launch_bounds__(256) void stats_hist_kernel(
    const float* __restrict__ ftq, const float* __restrict__ ftk,
    float* __restrict__ sums, unsigned short* __restrict__ xqb,
    unsigned short* __restrict__ xkb,
    const int* __restrict__ dstE, unsigned short* __restrict__ rankE,
    unsigned short* __restrict__ hmat, unsigned short* __restrict__ ctot){
  __shared__ float red[4*FEATS];               // 2 KB
  __shared__ unsigned lh[HQ/2];                // 12544 u16 bins packed -> 25088 B
  int tid = threadIdx.x, bid = blockIdx.x;
  if (bid < STAT_BLOCKS){
    for (int i = tid; i < 4*FEATS; i += 256) red[i] = 0.f;
    __syncthreads();
    int sub = tid >> 5, c4 = tid & 31;         // 32 lanes cover one 128-f row
    const float* Xs = (sub < 4) ? ftq : ftk;
    unsigned short* Xb = (sub < 4) ? xqb : xkb;
    int so = (sub < 4) ? 0 : 2*FEATS;
    float a0=0,a1=0,a2=0,a3=0,b0=0,b1=0,b2=0,b3=0;
    #pragma unroll 4
    for (int r = bid*4 + (sub&3); r < N_NODES; r += STAT_BLOCKS*4){
      float4 x = *(const float4*)(Xs + (size_t)r*FEATS + c4*4);
      // bf16 A rows for both GEMM planes (same RNE as GEMM-side cvt)
      *(uint2*)&Xb[(size_t)r*FEATS + c4*4] = make_uint2(cvtpk(x.x,x.y), cvtpk(x.z,x.w));
      a0+=x.x; b0+=x.x*x.x; a1+=x.y; b1+=x.y*x.y;
      a2+=x.z; b2+=x.z*x.z; a3+=x.w; b3+=x.w*x.w;
    }
    a0 += __shfl_xor(a0,32); a1 += __shfl_xor(a1,32);
    a2 += __shfl_xor(a2,32); a3 += __shfl_xor(a3,32);
    b0 += __shfl_xor(b0,32); b1 += __shfl_xor(b1,32);
    b2 += __shfl_xor(b2,32); b3 += __shfl_xor(b3,32);
    if ((tid & 63) < 32){
      int c0 = c4*4;
      atomicAdd(&red[so + c0+0], a0); atomicAdd(&red[so + c0+1], a1);
      atomicAdd(&red[so + c0+2], a2); atomicAdd(&red[so + c0+3], a3);
      atomicAdd(&red[so + FEATS + c0+0], b0); atomicAdd(&red[so + FEATS + c0+1], b1);
      atomicAdd(&red[so + FEATS + c0+2], b2); atomicAdd(&red[so + FEATS + c0+3], b3);
    }
    __syncthreads();
    for (int i = tid; i < 4*FEATS; i += 256) atomicAdd(&sums[i], red[i]);
  } else {
    int hb = bid - STAT_BLOCKS;                // 0..511
    int seg = hb >> 2, q = hb & 3;
    int dlo = q * HQ;
    for (int i = tid; i < HQ/2; i += 256) lh[i] = 0;
    __syncthreads();
    int e0 = seg * ESEG;
    for (int t = e0 + tid; t < e0 + ESEG; t += 256){
      int d = dstE[t] - dlo;
      if ((unsigned)d < (unsigned)HQ){
        unsigned sh = (d & 1) * 16;
        unsigned old = atomicAdd(&lh[d >> 1], 1u << sh);
        rankE[t] = (unsigned short)((old >> sh) & 0xffffu);   // local rank in (seg,d)
      }
    }
    __syncthreads();
    unsigned* row = (unsigned*)(hmat + (size_t)hb * HQ);
    for (int i = tid; i < HQ/2; i += 256) row[i] = lh[i];
    // per-chunk totals -> ctot (plain stores, no atomics)
    int wv = tid >> 6, ln = tid & 63;
    for (int c = wv; c < CPQ; c += 4){
      unsigned w0 = lh[c*128 + ln];
      unsigned w1 = lh[c*128 + 64 + ln];
      unsigned t = (w0 & 0xffffu) + (w0 >> 16) + (w1 & 0xffffu) + (w1 >> 16);
      #pragma unroll
      for (int o = 1; o < 64; o <<= 1) t += __shfl_xor((int)t, o);
      if (ln == 0) ctot[hb*CPQ + c] = (unsigned short)t;   // total <= 6250 fits u16
    }
  }
}

// ---------------- node 2: colscan + chunk scan (0..195) || BN-fold (196..291) || bscan (292)
__global__ __launch_bounds__(256) void colscan_fold_kernel(
    const unsigned short* __restrict__ hmat, unsigned short* __restrict__ hbase,
    int* __restrict__ loc, const unsigned short* __restrict__ ctot, int* __restrict__ bscan,
    const float* __restrict__ Wq, const float* __restrict__ bq,
    const float* __restrict__ Wk, const float* __restrict__ Wv,
    const float* __restrict__ gq, const float* __restrict__ bqn,
    const float* __restrict__ gk, const float* __restrict__ bkn,
    const float* __restrict__ sums,
    unsigned short* __restrict__ Wb, float* __restrict__ bias){
  __shared__ int s[256];
  int tid = threadIdx.x, bid = blockIdx.x;
  if (bid < NCHUNK){
    int q = bid / CPQ;                         // chunks never straddle quarters (49*256=12544)
    int d = bid*256 + tid;
    int col = d - q*HQ;
    const unsigned short* hp = hmat + (size_t)q*HQ + col;   // row hb = seg*4+q
    unsigned short* bp = hbase + (size_t)q*HQ + col;
    int run = 0;
    #pragma unroll 8
    for (int sg = 0; sg < HSEG; sg++){
      int v = hp[(size_t)sg*4*HQ];
      bp[(size_t)sg*4*HQ] = (unsigned short)run;   // exclusive prefix over segments
      run += v;
    }
    s[tid] = run; __syncthreads();
    for (int dd = 1; dd < 256; dd <<= 1){
      int tv = (tid >= dd) ? s[tid-dd] : 0; __syncthreads();
      s[tid] += tv; __syncthreads();
    }
    loc[d] = s[tid] - run;                     // chunk-local exclusive
  } else if (bid == NCHUNK + 96){              // bscan block: reduce ctot, ladder-scan
    int v = 0;
    if (tid < NCHUNK){
      int q = tid / CPQ, cc = tid - q*CPQ;
      const unsigned short* cp = ctot + q*CPQ + cc;   // row hb = seg*4+q
      #pragma unroll 8
      for (int sg = 0; sg < HSEG; sg++) v += cp[(size_t)sg*4*CPQ];
    }
    s[tid] = v; __syncthreads();
    for (int dd = 1; dd < 256; dd <<= 1){
      int tv = (tid >= dd) ? s[tid-dd] : 0; __syncthreads();
      s[tid] += tv; __syncthreads();
    }
    if (tid < NCHUNK) bscan[tid] = s[tid] - v;
  } else {
    int wv = (bid - NCHUNK)*4 + (tid >> 6);    // 0..383
    int lane = tid & 63;
    int m = wv >> 7;                           // 0=q,1=v,2=k
    int o = wv & 127;
    const float* Wsrc = (m==0) ? Wq : (m==1) ? Wv : Wk;
    const float* g   = (m==2) ? gk : gq;
    const float* bb  = (m==2) ? bkn : bqn;
    const float* s0  = (m==2) ? (sums + 2*FEATS) : sums;
    const float invN = 1.0f / (float)N_NODES;
    float acc = 0.f;
    unsigned short w2[2];
    int i0 = lane*2;
    #pragma unroll
    for (int t = 0; t < 2; t++){
      int i = i0 + t;
      float mean = s0[i]*invN;
      float var  = s0[FEATS+i]*invN - mean*mean;
      float rstd = rsqrtf(var + 1e-5f);
      float scale = g[i]*rstd;
      float shift = bb[i] - mean*scale;
      float w = Wsrc[o*FEATS + i];
      w2[t] = f2bf(w*scale);
      acc += shift*w;
    }
    ((unsigned*)Wb)[(m*FEATS*FEATS + o*FEATS + i0) >> 1] =
        (unsigned)w2[0] | ((unsigned)w2[1] << 16);
    #pragma unroll
    for (int off = 1; off < 64; off <<= 1) acc += __shfl_xor(acc, off);
    if (lane == 0) bias[m*FEATS + o] = acc + ((m==0) ? bq[o] : 0.f);
  }
}

// ---------------- node 3: fully atomic-free CSR scatter (no LDS, tiny VGPR -> full occupancy)
__global__ __launch_bounds__(256) void scatter_kernel(
    const int* __restrict__ dstE, const int* __restrict__ srcE,
    const int* __restrict__ loc, const int* __restrict__ bscan,
    const unsigned short* __restrict__ rankE, const unsigned short* __restrict__ hbase,
    int* __restrict__ src_csr){
  int t = blockIdx.x*256 + threadIdx.x;        // exactly covers N_EDGES
  int d = dstE[t];
  int seg = t / ESEG;
  int q = d / HQ;
  int base = (int)hbase[(size_t)(seg*4 + q)*HQ + (d - q*HQ)];
  src_csr[loc[d] + bscan[d >> 8] + base + (int)rankE[t]] = srcE[t];
}

// ---------------- node 4: merged-plane GEMM, all-bf16 A (branchless loadA)
// blocks 0..195:  A=xqb, B = {Wq, Wv} both staged -> q and v outputs
// blocks 196..391: A=xkb, B = {Wk}               -> k output
__global__ __launch_bounds__(256) void gemm_kernel(
    const unsigned short* __restrict__ xqb, const unsigned short* __restrict__ xkb,
    const unsigned short* __restrict__ Wball, const float* __restrict__ biasall,
    unsigned short* __restrict__ qv, unsigned short* __restrict__ kb){
  __shared__ unsigned short Bs[2][FEATS][FEATS];   // 64KB, XOR-swizzled 16B chunks
  int tid = threadIdx.x, bid = blockIdx.x;
  int isk = (bid >= GEMM_BX);
  int bx = isk ? bid - GEMM_BX : bid;
  int nplanes = isk ? 1 : 2;
  { // stage B plane(s) with chunk-XOR swizzle: chunk' = chunk ^ (row&15)
    for (int p = 0; p < nplanes; p++){
      int m = isk ? 2 : p;
      const uint4* srcp = (const uint4*)(Wball + m*FEATS*FEATS);
      for (int idx = tid; idx < FEATS*FEATS/8; idx += 256){
        int n = idx >> 4, ck = idx & 15;
        *(uint4*)&Bs[p][n][(ck ^ (n & 15))*8] = srcp[idx];
      }
    }
  }
  __syncthreads();                              // only barrier in the kernel
  int wave = tid >> 6, lane = tid & 63;
  int mrow = lane & 15, quad = lane >> 4;
  const unsigned short* Xb = isk ? xkb : xqb;   // both bf16, padded to 50176 rows
  float bv[2][8];
  #pragma unroll
  for (int p = 0; p < 2; p++)
    #pragma unroll
    for (int ct = 0; ct < 8; ct++)
      bv[p][ct] = biasall[(isk ? 2 : p)*FEATS + ct*16 + mrow];
  uint4 cur[4], nxt[4];
  auto loadA = [&](uint4* buf, int t){
    int arow = t*64 + wave*16 + mrow;
    const unsigned short* xp = Xb + (size_t)arow*FEATS + quad*8;  // padded rows
    buf[0] = *(const uint4*)xp;
    buf[1] = *(const uint4*)(xp + 32);
    buf[2] = *(const uint4*)(xp + 64);
    buf[3] = *(const uint4*)(xp + 96);
  };
  loadA(cur, bx);
  for (int t = bx; t < NTILE; t += GEMM_BX){
    int tn = t + GEMM_BX;
    if (tn < NTILE) loadA(nxt, tn);             // prefetch next A tile under MFMA
    f32x4 acc[2][8];
    #pragma unroll
    for (int p = 0; p < 2; p++)
      #pragma unroll
      for (int i = 0; i < 8; i++) acc[p][i] = (f32x4){0.f,0.f,0.f,0.f};
    #pragma unroll
    for (int kt = 0; kt < 4; kt++){
      pack8 a; a.u = cur[kt];
      #pragma unroll
      for (int ct = 0; ct < 8; ct++){
        bf16x8 b0 = *(bf16x8*)&Bs[0][ct*16 + mrow][((kt*4 + quad) ^ mrow)*8];
        acc[0][ct] = __builtin_amdgcn_mfma_f32_16x16x32_bf16(a.v, b0, acc[0][ct], 0, 0, 0);
      }
      if (!isk){
        #pragma unroll
        for (int ct = 0; ct < 8; ct++){
          bf16x8 b1 = *(bf16x8*)&Bs[1][ct*16 + mrow][((kt*4 + quad) ^ mrow)*8];
          acc[1][ct] = __builtin_amdgcn_mfma_f32_16x16x32_bf16(a.v, b1, acc[1][ct], 0, 0, 0);
        }
      }
    }
    int row0 = t*64;
    #pragma unroll
    for (int p = 0; p < 2; p++){
      if (isk && p) break;
      unsigned short* Out = isk ? kb : (qv + p*128);
      const int ostride = isk ? FEATS : 256;
      #pragma unroll
      for (int ct = 0; ct < 8; ct++){
        int col = ct*16 + mrow;
        #pragma unroll
        for (int v = 0; v < 4; v++){
          int orow = row0 + wave*16 + quad*4 + v;
          float sv = acc[p][ct][v] + bv[p][ct];
          float pf = __shfl_xor(sv, 1);         // partner col's f32 sum
          if (!(mrow & 1) && orow < N_NODES)
            *(unsigned*)&Out[(size_t)orow*ostride + col] = cvtpk(sv, pf);
        }
      }
    }
    #pragma unroll
    for (int i = 0; i < 4; i++) cur[i] = nxt[i];
  }
}

// ---------------- node 5: per-dst-node scores + max-free softmax agg (static interleave)
__global__ __launch_bounds__(256) void node_fused_kernel(
    const unsigned short* __restrict__ qv, const unsigned short* __restrict__ kb,
    const float* __restrict__ attn, const int* __restrict__ src_csr,
    const int* __restrict__ loc, const int* __restrict__ bscan,
    float* __restrict__ out){
  int tid = threadIdx.x;
  int lane = tid & 63;
  int h = lane & 7, g = lane >> 3;
  int w = blockIdx.x*4 + (tid >> 6);
  const float L2E = 1.44269504f;
  float ar[16];
  {
    const uint4* ap = (const uint4*)(attn + h*16);
    uint4 a0 = ap[0], a1 = ap[1], a2 = ap[2], a3 = ap[3];
    ar[0]=__uint_as_float(a0.x); ar[1]=__uint_as_float(a0.y); ar[2]=__uint_as_float(a0.z); ar[3]=__uint_as_float(a0.w);
    ar[4]=__uint_as_float(a1.x); ar[5]=__uint_as_float(a1.y); ar[6]=__uint_as_float(a1.z); ar[7]=__uint_as_float(a1.w);
    ar[8]=__uint_as_float(a2.x); ar[9]=__uint_as_float(a2.y); ar[10]=__uint_as_float(a2.z); ar[11]=__uint_as_float(a2.w);
    ar[12]=__uint_as_float(a3.x); ar[13]=__uint_as_float(a3.y); ar[14]=__uint_as_float(a3.z); ar[15]=__uint_as_float(a3.w);
  }
  for (int n = w; n < N_NODES; n += NF_WAVES){
    int off0 = loc[n]   + bscan[n>>8];
    int off1 = loc[n+1] + bscan[(n+1)>>8];      // loc[50000] valid (padded chunk 195)
    int deg = off1 - off0;
    if (deg == 0){
      ((float2*)(out + (size_t)n*FEATS))[lane] = make_float2(0.f, 0.f);
      continue;
    }
    float kf2[16];
    {
      const unsigned short* kr = kb + (size_t)n*FEATS + h*16;
      uint4 k0 = *(const uint4*)kr;
      uint4 k1 = *(const uint4*)(kr + 8);
      float kf[16]; unpack8(k0, kf); unpack8(k1, kf+8);
      #pragma unroll
      for (int i = 0; i < 16; i++) kf2[i] = -L2E * kf[i];
    }
    float ssum = 0.f;
    float acc[16];
    #pragma unroll
    for (int i = 0; i < 16; i++) acc[i] = 0.f;
    if (g < deg){
      int sA = src_csr[off0 + g];
      int jB = g + 8;
      int sB = (jB < deg) ? src_csr[off0 + jB] : sA;   // dup tail -> L1 hit
      const unsigned short* pA = qv + (size_t)sA*256 + h*16;
      uint4 qa0 = *(const uint4*)pA;
      uint4 qa1 = *(const uint4*)(pA + 8);
      while (true){
        uint4 va0 = *(const uint4*)(pA + 128);   // current v (interleaved row)
        uint4 va1 = *(const uint4*)(pA + 136);
        const unsigned short* pB = qv + (size_t)sB*256 + h*16;
        uint4 qb0 = *(const uint4*)pB;           // next q prefetch
        uint4 qb1 = *(const uint4*)(pB + 8);
        int jC = jB + 8;
        int sC = (jC < deg) ? src_csr[off0 + jC] : sB;
        float qf[16]; unpack8(qa0, qf); unpack8(qa1, qf+8);
        float ta = 0.f, tb = 0.f, tc = 0.f, td = 0.f;
        #pragma unroll
        for (int i = 0; i < 16; i += 4){
          float x0 = fmaf(qf[i+0], -L2E, kf2[i+0]);
          float x1 = fmaf(qf[i+1], -L2E, kf2[i+1]);
          float x2 = fmaf(qf[i+2], -L2E, kf2[i+2]);
          float x3 = fmaf(qf[i+3], -L2E, kf2[i+3]);
          ta = fmaf(ar[i+0], __builtin_amdgcn_rcpf(1.f + __builtin_amdgcn_exp2f(x0)), ta);
          tb = fmaf(ar[i+1], __builtin_amdgcn_rcpf(1.f + __builtin_amdgcn_exp2f(x1)), tb);
          tc = fmaf(ar[i+2], __builtin_amdgcn_rcpf(1.f + __builtin_amdgcn_exp2f(x2)), tc);
          td = fmaf(ar[i+3], __builtin_amdgcn_rcpf(1.f + __builtin_amdgcn_exp2f(x3)), td);
        }
        float t = (ta + tb) + (tc + td);
        float ex = __builtin_amdgcn_exp2f(t * L2E);   // |t|<=sum|attn| -> max-free safe
        ssum += ex;
        float vf[16]; unpack8(va0, vf); unpack8(va1, vf+8);
        #pragma unroll
        for (int i = 0; i < 16; i++) acc[i] = fmaf(ex, vf[i], acc[i]);
        if (jB >= deg) break;
        qa0 = qb0; qa1 = qb1; pA = pB;
        jB = jC; sB = sC;
      }
    }
    ssum += __shfl_xor(ssum, 8); ssum += __shfl_xor(ssum, 16); ssum += __shfl_xor(ssum, 32);
    #pragma unroll
    for (int i = 0; i < 16; i++){
      acc[i] += __shfl_xor(acc[i], 8);
      acc[i] += __shfl_xor(acc[i], 16);
      acc[i] += __shfl_xor(acc[i], 32);
    }
    if (g == 0){
      float inv_s = 1.f / ssum;
      float4* op = (float4*)(out + (size_t)n*FEATS + h*16);
      op[0] = make_float4(acc[0]*inv_s, acc[1]*inv_s, acc[2]*inv_s, acc[3]*inv_s);
      op[1] = make_float4(acc[4]*inv_s, acc[5]*inv_s, acc[6]*inv_s, acc[7]*inv_s);
      op[2] = make_float4(acc[8]*inv_s, acc[9]*inv_s, acc[10]*inv_s, acc[11]*inv_s);
      op[3] = make_float4(acc[12]*inv_s, acc[13]*inv_s, acc[14]*inv_s, acc[15]*inv_s);
    }
  }
}

extern "C" void kernel_launch(void* const* d_in, const int* in_sizes, int n_in,
                              void* d_out, int out_size, void* d_ws, size_t ws_size,
                              hipStream_t stream){
  (void)in_sizes; (void)n_in; (void)out_size; (void)ws_size;
  const float* ftq  = (const float*)d_in[0];
  const float* ftk  = (const float*)d_in[1];
  const int*   srcE = (const int*)d_in[2];
  const int*   dstE = (const int*)d_in[3];
  const float* Wq   = (const float*)d_in[4];
  const float* bq   = (const float*)d_in[5];
  const float* Wk   = (const float*)d_in[6];
  const float* Wv   = (const float*)d_in[7];
  const float* attn = (const float*)d_in[8];
  const float* gq   = (const float*)d_in[9];
  const float* bqn  = (const float*)d_in[10];
  const float* gk   = (const float*)d_in[11];
  const float* bkn  = (const float*)d_in[12];

  char* ws = (char*)d_ws;
  float* sums    = (float*)(ws + 0);             // 512 f     [0, 2048)  <- only memset
  int*   bscan   = (int*)(ws + 2048);            // 196 i     -> 2832
  int*   loc     = (int*)(ws + 4096);            // CPAD i    -> 204800
  int*   src_csr = (int*)(ws + 204800);          // 800000 i  -> 3404800
  unsigned short* rankE = (unsigned short*)(ws + 3404800);   // 800000 u16 -> 5004800
  unsigned short* hmat  = (unsigned short*)(ws + 5004800);   // 512*12544 u16 -> 17849856
  unsigned short* hbase = (unsigned short*)(ws + 17849856);  // 512*12544 u16 -> 30694912
  unsigned short* ctot  = (unsigned short*)(ws + 30694912);  // 512*49 u16 -> 30745088
  unsigned short* Wb    = (unsigned short*)(ws + 30745088);  // 3*16384 u16 -> 30843392
  float* biasf   = (float*)(ws + 30843392);      // 384 f -> 30844928
  unsigned short* xqb = (unsigned short*)(ws + 30844928);    // 50176*128 u16 -> 43689984
  unsigned short* xkb = (unsigned short*)(ws + 43689984);    // 50176*128 u16 -> 56535040
  unsigned short* qv  = (unsigned short*)(ws + 56535040);    // 50000*256 u16 -> 82135040
  unsigned short* kb  = (unsigned short*)(ws + 82135040);    // 50000*128 u16 -> 94935040
  float* out = (float*)d_out;

  hipMemsetAsync(ws, 0, 2048, stream);  // sums only

  hipLaunchKernelGGL(stats_hist_kernel, dim3(STAT_BLOCKS + HIST_BLOCKS), dim3(256), 0, stream,
                     ftq, ftk, sums, xqb, xkb, dstE, rankE, hmat, ctot);
  hipLaunchKernelGGL(colscan_fold_kernel, dim3(NCHUNK + 97), dim3(256), 0, stream,
                     hmat, hbase, loc, ctot, bscan,
                     Wq, bq, Wk, Wv, gq, bqn, gk, bkn, sums, Wb, biasf);
  hipLaunchKernelGGL(scatter_kernel, dim3(SCAT_BLOCKS), dim3(256), 0, stream,
                     dstE, srcE, loc, bscan, rankE, hbase, src_csr);
  hipLaunchKernelGGL(gemm_kernel, dim3(GEMM_BLOCKS), dim3(256), 0, stream,
                     xqb, xkb, Wb, biasf, qv, kb);
  hipLaunchKernelGGL(node_fused_kernel, dim3(NF_WAVES/4), dim3(256), 0, stream,
                     qv, kb, attn, src_csr, loc, bscan, out);
}

// Round 12
// 261.569 us; speedup vs baseline: 1.8414x; 1.0538x over previous
//
#include <hip/hip_runtime.h>

#define N_NODES 50000
#define N_EDGES 800000
#define FEATS 128
#define NCHUNK 196            // ceil(50000/256)
#define CPAD 50176            // NCHUNK*256 (loc padded)
#define GEMM_BX 196
#define GEMM_BLOCKS 392       // 196 qv-merged + 196 k
#define SCAT_BLOCKS 3125      // 3125*256 = 800000 exactly
#define NTILE 782             // ceil(50000/64)
#define NF_WAVES 8192
#define STAT_BLOCKS 512
#define HIST_BLOCKS 512       // 128 segments x 4 quarter-ranges
#define HSEG 128
#define ESEG 6250
#define HQ 12544              // bins per quarter (4*12544 = 50176 = CPAD)
#define CPQ 49                // chunks per quarter (12544/256)

typedef __attribute__((ext_vector_type(8))) short bf16x8;
typedef __attribute__((ext_vector_type(4))) float f32x4;
typedef __attribute__((ext_vector_type(2))) float f32x2;
typedef __attribute__((ext_vector_type(4))) unsigned u32x4;   // native vec for nontemporal builtins
typedef union { uint4 u; bf16x8 v; } pack8;

__device__ __forceinline__ unsigned short f2bf(float f){
  unsigned u = __float_as_uint(f);
  u += 0x7FFF + ((u >> 16) & 1);           // RNE
  return (unsigned short)(u >> 16);
}
// HW packed f32->bf16 (RNE), 2 values / inst
__device__ __forceinline__ unsigned cvtpk(float lo, float hi){
  unsigned r;
  asm("v_cvt_pk_bf16_f32 %0, %1, %2" : "=v"(r) : "v"(lo), "v"(hi));
  return r;
}
// bf16 pair unpack, 1 VALU op per float
__device__ __forceinline__ void unpack8(uint4 p, float* f){
  f[0]=__uint_as_float(p.x << 16); f[1]=__uint_as_float(p.x & 0xffff0000u);
  f[2]=__uint_as_float(p.y << 16); f[3]=__uint_as_float(p.y & 0xffff0000u);
  f[4]=__uint_as_float(p.z << 16); f[5]=__uint_as_float(p.z & 0xffff0000u);
  f[6]=__uint_as_float(p.w << 16); f[7]=__uint_as_float(p.w & 0xffff0000u);
}
__device__ __forceinline__ void unpack8v(u32x4 p, float* f){
  f[0]=__uint_as_float(p.x << 16); f[1]=__uint_as_float(p.x & 0xffff0000u);
  f[2]=__uint_as_float(p.y << 16); f[3]=__uint_as_float(p.y & 0xffff0000u);
  f[4]=__uint_as_float(p.z << 16); f[5]=__uint_as_float(p.z & 0xffff0000u);
  f[6]=__uint_as_float(p.w << 16); f[7]=__uint_as_float(p.w & 0xffff0000u);
}

// ---------------- node 1: BN stats + bf16 q-emit (0..511) || quarter-hist + rank + ctot (512..1023)
__global__ __launch_bounds__(256) void stats_hist_kernel(
    const float* __restrict__ ftq, const float* __restrict__ ftk,
    float* __restrict__ sums, unsigned short* __restrict__ xqb,
    const int* __restrict__ dstE, unsigned short* __restrict__ rankE,
    unsigned short* __restrict__ hmat, unsigned short* __restrict__ ctot){
  __shared__ float red[4*FEATS];               // 2 KB
  __shared__ unsigned lh[HQ/2];                // 12544 u16 bins packed -> 25088 B
  int tid = threadIdx.x, bid = blockIdx.x;
  if (bid < STAT_BLOCKS){
    for (int i = tid; i < 4*FEATS; i += 256) red[i] = 0.f;
    __syncthreads();
    int sub = tid >> 5, c4 = tid & 31;         // 32 lanes cover one 128-f row
    const float* Xs = (sub < 4) ? ftq : ftk;
    int so = (sub < 4) ? 0 : 2*FEATS;
    bool isq = (sub < 4);
    float a0=0,a1=0,a2=0,a3=0,b0=0,b1=0,b2=0,b3=0;
    #pragma unroll 4
    for (int r = bid*4 + (sub&3); r < N_NODES; r += STAT_BLOCKS*4){
      float4 x = *(const float4*)(Xs + (size_t)r*FEATS + c4*4);
      if (isq)  // bf16 A rows for qv GEMM plane (same RNE as GEMM-side cvt)
        *(uint2*)&xqb[(size_t)r*FEATS + c4*4] = make_uint2(cvtpk(x.x,x.y), cvtpk(x.z,x.w));
      a0+=x.x; b0+=x.x*x.x; a1+=x.y; b1+=x.y*x.y;
      a2+=x.z; b2+=x.z*x.z; a3+=x.w; b3+=x.w*x.w;
    }
    a0 += __shfl_xor(a0,32); a1 += __shfl_xor(a1,32);
    a2 += __shfl_xor(a2,32); a3 += __shfl_xor(a3,32);
    b0 += __shfl_xor(b0,32); b1 += __shfl_xor(b1,32);
    b2 += __shfl_xor(b2,32); b3 += __shfl_xor(b3,32);
    if ((tid & 63) < 32){
      int c0 = c4*4;
      atomicAdd(&red[so + c0+0], a0); atomicAdd(&red[so + c0+1], a1);
      atomicAdd(&red[so + c0+2], a2); atomicAdd(&red[so + c0+3], a3);
      atomicAdd(&red[so + FEATS + c0+0], b0); atomicAdd(&red[so + FEATS + c0+1], b1);
      atomicAdd(&red[so + FEATS + c0+2], b2); atomicAdd(&red[so + FEATS + c0+3], b3);
    }
    __syncthreads();
    for (int i = tid; i < 4*FEATS; i += 256) atomicAdd(&sums[i], red[i]);
  } else {
    int hb = bid - STAT_BLOCKS;                // 0..511
    int seg = hb >> 2, q = hb & 3;
    int dlo = q * HQ;
    for (int i = tid; i < HQ/2; i += 256) lh[i] = 0;
    __syncthreads();
    int e0 = seg * ESEG;
    for (int t = e0 + tid; t < e0 + ESEG; t += 256){
      int d = dstE[t] - dlo;
      if ((unsigned)d < (unsigned)HQ){
        unsigned sh = (d & 1) * 16;
        unsigned old = atomicAdd(&lh[d >> 1], 1u << sh);
        rankE[t] = (unsigned short)((old >> sh) & 0xffffu);   // local rank in (seg,d)
      }
    }
    __syncthreads();
    unsigned* row = (unsigned*)(hmat + (size_t)hb * HQ);
    for (int i = tid; i < HQ/2; i += 256) row[i] = lh[i];
    // per-chunk totals -> ctot (plain stores, no atomics)
    int wv = tid >> 6, ln = tid & 63;
    for (int c = wv; c < CPQ; c += 4){
      unsigned w0 = lh[c*128 + ln];
      unsigned w1 = lh[c*128 + 64 + ln];
      unsigned t = (w0 & 0xffffu) + (w0 >> 16) + (w1 & 0xffffu) + (w1 >> 16);
      #pragma unroll
      for (int o = 1; o < 64; o <<= 1) t += __shfl_xor((int)t, o);
      if (ln == 0) ctot[hb*CPQ + c] = (unsigned short)t;   // total <= 6250 fits u16
    }
  }
}

// ---------------- node 2: colscan + chunk scan (0..195) || BN-fold (196..291) || bscan (292)
__global__ __launch_bounds__(256) void colscan_fold_kernel(
    const unsigned short* __restrict__ hmat, unsigned short* __restrict__ hbase,
    int* __restrict__ loc, const unsigned short* __restrict__ ctot, int* __restrict__ bscan,
    const float* __restrict__ Wq, const float* __restrict__ bq,
    const float* __restrict__ Wk, const float* __restrict__ Wv,
    const float* __restrict__ gq, const float* __restrict__ bqn,
    const float* __restrict__ gk, const float* __restrict__ bkn,
    const float* __restrict__ sums,
    unsigned short* __restrict__ Wb, float* __restrict__ bias){
  __shared__ int s[256];
  int tid = threadIdx.x, bid = blockIdx.x;
  if (bid < NCHUNK){
    int q = bid / CPQ;                         // chunks never straddle quarters (49*256=12544)
    int d = bid*256 + tid;
    int col = d - q*HQ;
    const unsigned short* hp = hmat + (size_t)q*HQ + col;   // row hb = seg*4+q
    unsigned short* bp = hbase + (size_t)q*HQ + col;
    int run = 0;
    #pragma unroll 8
    for (int sg = 0; sg < HSEG; sg++){
      int v = hp[(size_t)sg*4*HQ];
      bp[(size_t)sg*4*HQ] = (unsigned short)run;   // exclusive prefix over segments
      run += v;
    }
    s[tid] = run; __syncthreads();
    for (int dd = 1; dd < 256; dd <<= 1){
      int tv = (tid >= dd) ? s[tid-dd] : 0; __syncthreads();
      s[tid] += tv; __syncthreads();
    }
    loc[d] = s[tid] - run;                     // chunk-local exclusive
  } else if (bid == NCHUNK + 96){              // bscan block: reduce ctot, ladder-scan
    int v = 0;
    if (tid < NCHUNK){
      int q = tid / CPQ, cc = tid - q*CPQ;
      const unsigned short* cp = ctot + q*CPQ + cc;   // row hb = seg*4+q
      #pragma unroll 8
      for (int sg = 0; sg < HSEG; sg++) v += cp[(size_t)sg*4*CPQ];
    }
    s[tid] = v; __syncthreads();
    for (int dd = 1; dd < 256; dd <<= 1){
      int tv = (tid >= dd) ? s[tid-dd] : 0; __syncthreads();
      s[tid] += tv; __syncthreads();
    }
    if (tid < NCHUNK) bscan[tid] = s[tid] - v;
  } else {
    int wv = (bid - NCHUNK)*4 + (tid >> 6);    // 0..383
    int lane = tid & 63;
    int m = wv >> 7;                           // 0=q,1=v,2=k
    int o = wv & 127;
    const float* Wsrc = (m==0) ? Wq : (m==1) ? Wv : Wk;
    const float* g   = (m==2) ? gk : gq;
    const float* bb  = (m==2) ? bkn : bqn;
    const float* s0  = (m==2) ? (sums + 2*FEATS) : sums;
    const float invN = 1.0f / (float)N_NODES;
    float acc = 0.f;
    unsigned short w2[2];
    int i0 = lane*2;
    #pragma unroll
    for (int t = 0; t < 2; t++){
      int i = i0 + t;
      float mean = s0[i]*invN;
      float var  = s0[FEATS+i]*invN - mean*mean;
      float rstd = rsqrtf(var + 1e-5f);
      float scale = g[i]*rstd;
      float shift = bb[i] - mean*scale;
      float w = Wsrc[o*FEATS + i];
      w2[t] = f2bf(w*scale);
      acc += shift*w;
    }
    ((unsigned*)Wb)[(m*FEATS*FEATS + o*FEATS + i0) >> 1] =
        (unsigned)w2[0] | ((unsigned)w2[1] << 16);
    #pragma unroll
    for (int off = 1; off < 64; off <<= 1) acc += __shfl_xor(acc, off);
    if (lane == 0) bias[m*FEATS + o] = acc + ((m==0) ? bq[o] : 0.f);
  }
}

// ---------------- node 3: fully atomic-free CSR scatter (no LDS, tiny VGPR -> full occupancy)
__global__ __launch_bounds__(256) void scatter_kernel(
    const int* __restrict__ dstE, const int* __restrict__ srcE,
    const int* __restrict__ loc, const int* __restrict__ bscan,
    const unsigned short* __restrict__ rankE, const unsigned short* __restrict__ hbase,
    int* __restrict__ src_csr){
  int t = blockIdx.x*256 + threadIdx.x;        // exactly covers N_EDGES
  int d = dstE[t];
  int seg = t / ESEG;
  int q = d / HQ;
  int base = (int)hbase[(size_t)(seg*4 + q)*HQ + (d - q*HQ)];
  src_csr[loc[d] + bscan[d >> 8] + base + (int)rankE[t]] = srcE[t];
}

// ---------------- node 4: merged-plane GEMM
// blocks 0..195:  A=xqb (bf16, no convert), B = {Wq, Wv} both staged -> q and v outputs
// blocks 196..391: A=ftk (f32 + cvtpk),     B = {Wk}                 -> k output
__global__ __launch_bounds__(256) void gemm_kernel(
    const unsigned short* __restrict__ xqb, const float* __restrict__ ftk,
    const unsigned short* __restrict__ Wball, const float* __restrict__ biasall,
    unsigned short* __restrict__ qv, unsigned short* __restrict__ kb){
  __shared__ unsigned short Bs[2][FEATS][FEATS];   // 64KB, XOR-swizzled 16B chunks
  int tid = threadIdx.x, bid = blockIdx.x;
  int isk = (bid >= GEMM_BX);
  int bx = isk ? bid - GEMM_BX : bid;
  int nplanes = isk ? 1 : 2;
  { // stage B plane(s) with chunk-XOR swizzle: chunk' = chunk ^ (row&15)
    for (int p = 0; p < nplanes; p++){
      int m = isk ? 2 : p;
      const uint4* srcp = (const uint4*)(Wball + m*FEATS*FEATS);
      for (int idx = tid; idx < FEATS*FEATS/8; idx += 256){
        int n = idx >> 4, ck = idx & 15;
        *(uint4*)&Bs[p][n][(ck ^ (n & 15))*8] = srcp[idx];
      }
    }
  }
  __syncthreads();                              // only barrier in the kernel
  int wave = tid >> 6, lane = tid & 63;
  int mrow = lane & 15, quad = lane >> 4;
  float bv[2][8];
  #pragma unroll
  for (int p = 0; p < 2; p++)
    #pragma unroll
    for (int ct = 0; ct < 8; ct++)
      bv[p][ct] = biasall[(isk ? 2 : p)*FEATS + ct*16 + mrow];
  uint4 cur[4], nxt[4];
  auto loadA = [&](uint4* buf, int t){
    int arow = t*64 + wave*16 + mrow;
    if (!isk){
      const unsigned short* xp = xqb + (size_t)arow*FEATS + quad*8;  // padded rows
      buf[0] = *(const uint4*)xp;
      buf[1] = *(const uint4*)(xp + 32);
      buf[2] = *(const uint4*)(xp + 64);
      buf[3] = *(const uint4*)(xp + 96);
    } else {
      bool rok = arow < N_NODES;
      const float* xp = ftk + (size_t)(rok ? arow : 0)*FEATS + quad*8;
      #pragma unroll
      for (int kt = 0; kt < 4; kt++){
        float4 x0 = *(const float4*)(xp + kt*32);
        float4 x1 = *(const float4*)(xp + kt*32 + 4);
        if (!rok){ x0 = make_float4(0.f,0.f,0.f,0.f); x1 = x0; }
        buf[kt].x = cvtpk(x0.x, x0.y); buf[kt].y = cvtpk(x0.z, x0.w);
        buf[kt].z = cvtpk(x1.x, x1.y); buf[kt].w = cvtpk(x1.z, x1.w);
      }
    }
  };
  loadA(cur, bx);
  for (int t = bx; t < NTILE; t += GEMM_BX){
    int tn = t + GEMM_BX;
    if (tn < NTILE) loadA(nxt, tn);             // prefetch next A tile under MFMA
    f32x4 acc[2][8];
    #pragma unroll
    for (int p = 0; p < 2; p++)
      #pragma unroll
      for (int i = 0; i < 8; i++) acc[p][i] = (f32x4){0.f,0.f,0.f,0.f};
    #pragma unroll
    for (int kt = 0; kt < 4; kt++){
      pack8 a; a.u = cur[kt];
      #pragma unroll
      for (int ct = 0; ct < 8; ct++){
        bf16x8 b0 = *(bf16x8*)&Bs[0][ct*16 + mrow][((kt*4 + quad) ^ mrow)*8];
        acc[0][ct] = __builtin_amdgcn_mfma_f32_16x16x32_bf16(a.v, b0, acc[0][ct], 0, 0, 0);
      }
      if (!isk){
        #pragma unroll
        for (int ct = 0; ct < 8; ct++){
          bf16x8 b1 = *(bf16x8*)&Bs[1][ct*16 + mrow][((kt*4 + quad) ^ mrow)*8];
          acc[1][ct] = __builtin_amdgcn_mfma_f32_16x16x32_bf16(a.v, b1, acc[1][ct], 0, 0, 0);
        }
      }
    }
    int row0 = t*64;
    #pragma unroll
    for (int p = 0; p < 2; p++){
      if (isk && p) break;
      unsigned short* Out = isk ? kb : (qv + p*128);
      const int ostride = isk ? FEATS : 256;
      #pragma unroll
      for (int ct = 0; ct < 8; ct++){
        int col = ct*16 + mrow;
        #pragma unroll
        for (int v = 0; v < 4; v++){
          int orow = row0 + wave*16 + quad*4 + v;
          float sv = acc[p][ct][v] + bv[p][ct];
          float pf = __shfl_xor(sv, 1);         // partner col's f32 sum
          if (!(mrow & 1) && orow < N_NODES)
            *(unsigned*)&Out[(size_t)orow*ostride + col] = cvtpk(sv, pf);
        }
      }
    }
    #pragma unroll
    for (int i = 0; i < 4; i++) cur[i] = nxt[i];
  }
}

// ---------------- node 5: per-dst-node scores + max-free softmax agg (static interleave)
// nt-hints: kb rows (read once/node) and out (write once) bypass L2 -> keep qv resident
__global__ __launch_bounds__(256) void node_fused_kernel(
    const unsigned short* __restrict__ qv, const unsigned short* __restrict__ kb,
    const float* __restrict__ attn, const int* __restrict__ src_csr,
    const int* __restrict__ loc, const int* __restrict__ bscan,
    float* __restrict__ out){
  int tid = threadIdx.x;
  int lane = tid & 63;
  int h = lane & 7, g = lane >> 3;
  int w = blockIdx.x*4 + (tid >> 6);
  const float L2E = 1.44269504f;
  float ar[16];
  {
    const uint4* ap = (const uint4*)(attn + h*16);
    uint4 a0 = ap[0], a1 = ap[1], a2 = ap[2], a3 = ap[3];
    ar[0]=__uint_as_float(a0.x); ar[1]=__uint_as_float(a0.y); ar[2]=__uint_as_float(a0.z); ar[3]=__uint_as_float(a0.w);
    ar[4]=__uint_as_float(a1.x); ar[5]=__uint_as_float(a1.y); ar[6]=__uint_as_float(a1.z); ar[7]=__uint_as_float(a1.w);
    ar[8]=__uint_as_float(a2.x); ar[9]=__uint_as_float(a2.y); ar[10]=__uint_as_float(a2.z); ar[11]=__uint_as_float(a2.w);
    ar[12]=__uint_as_float(a3.x); ar[13]=__uint_as_float(a3.y); ar[14]=__uint_as_float(a3.z); ar[15]=__uint_as_float(a3.w);
  }
  for (int n = w; n < N_NODES; n += NF_WAVES){
    int off0 = loc[n]   + bscan[n>>8];
    int off1 = loc[n+1] + bscan[(n+1)>>8];      // loc[50000] valid (padded chunk 195)
    int deg = off1 - off0;
    if (deg == 0){
      f32x2 z = (f32x2){0.f, 0.f};
      __builtin_nontemporal_store(z, (f32x2*)(out + (size_t)n*FEATS) + lane);
      continue;
    }
    float kf2[16];
    {
      const unsigned short* kr = kb + (size_t)n*FEATS + h*16;
      u32x4 k0 = __builtin_nontemporal_load((const u32x4*)kr);
      u32x4 k1 = __builtin_nontemporal_load((const u32x4*)kr + 1);
      float kf[16]; unpack8v(k0, kf); unpack8v(k1, kf+8);
      #pragma unroll
      for (int i = 0; i < 16; i++) kf2[i] = -L2E * kf[i];
    }
    float ssum = 0.f;
    float acc[16];
    #pragma unroll
    for (int i = 0; i < 16; i++) acc[i] = 0.f;
    if (g < deg){
      int sA = src_csr[off0 + g];
      int jB = g + 8;
      int sB = (jB < deg) ? src_csr[off0 + jB] : sA;   // dup tail -> L1 hit
      const unsigned short* pA = qv + (size_t)sA*256 + h*16;
      uint4 qa0 = *(const uint4*)pA;
      uint4 qa1 = *(const uint4*)(pA + 8);
      while (true){
        uint4 va0 = *(const uint4*)(pA + 128);   // current v (interleaved row)
        uint4 va1 = *(const uint4*)(pA + 136);
        const unsigned short* pB = qv + (size_t)sB*256 + h*16;
        uint4 qb0 = *(const uint4*)pB;           // next q prefetch
        uint4 qb1 = *(const uint4*)(pB + 8);
        int jC = jB + 8;
        int sC = (jC < deg) ? src_csr[off0 + jC] : sB;
        float qf[16]; unpack8(qa0, qf); unpack8(qa1, qf+8);
        float ta = 0.f, tb = 0.f, tc = 0.f, td = 0.f;
        #pragma unroll
        for (int i = 0; i < 16; i += 4){
          float x0 = fmaf(qf[i+0], -L2E, kf2[i+0]);
          float x1 = fmaf(qf[i+1], -L2E, kf2[i+1]);
          float x2 = fmaf(qf[i+2], -L2E, kf2[i+2]);
          float x3 = fmaf(qf[i+3], -L2E, kf2[i+3]);
          ta = fmaf(ar[i+0], __builtin_amdgcn_rcpf(1.f + __builtin_amdgcn_exp2f(x0)), ta);
          tb = fmaf(ar[i+1], __builtin_amdgcn_rcpf(1.f + __builtin_amdgcn_exp2f(x1)), tb);
          tc = fmaf(ar[i+2], __builtin_amdgcn_rcpf(1.f + __builtin_amdgcn_exp2f(x2)), tc);
          td = fmaf(ar[i+3], __builtin_amdgcn_rcpf(1.f + __builtin_amdgcn_exp2f(x3)), td);
        }
        float t = (ta + tb) + (tc + td);
        float ex = __builtin_amdgcn_exp2f(t * L2E);   // |t|<=sum|attn| -> max-free safe
        ssum += ex;
        float vf[16]; unpack8(va0, vf); unpack8(va1, vf+8);
        #pragma unroll
        for (int i = 0; i < 16; i++) acc[i] = fmaf(ex, vf[i], acc[i]);
        if (jB >= deg) break;
        qa0 = qb0; qa1 = qb1; pA = pB;
        jB = jC; sB = sC;
      }
    }
    ssum += __shfl_xor(ssum, 8); ssum += __shfl_xor(ssum, 16); ssum += __shfl_xor(ssum, 32);
    #pragma unroll
    for (int i = 0; i < 16; i++){
      acc[i] += __shfl_xor(acc[i], 8);
      acc[i] += __shfl_xor(acc[i], 16);
      acc[i] += __shfl_xor(acc[i], 32);
    }
    if (g == 0){
      float inv_s = 1.f / ssum;
      f32x4* op = (f32x4*)(out + (size_t)n*FEATS + h*16);
      __builtin_nontemporal_store((f32x4){acc[0]*inv_s, acc[1]*inv_s, acc[2]*inv_s, acc[3]*inv_s}, op);
      __builtin_nontemporal_store((f32x4){acc[4]*inv_s, acc[5]*inv_s, acc[6]*inv_s, acc[7]*inv_s}, op+1);
      __builtin_nontemporal_store((f32x4){acc[8]*inv_s, acc[9]*inv_s, acc[10]*inv_s, acc[11]*inv_s}, op+2);
      __builtin_nontemporal_store((f32x4){acc[12]*inv_s, acc[13]*inv_s, acc[14]*inv_s, acc[15]*inv_s}, op+3);
    }
  }
}

extern "C" void kernel_launch(void* const* d_in, const int* in_sizes, int n_in,
                              void* d_out, int out_size, void* d_ws, size_t ws_size,
                              hipStream_t stream){
  (void)in_sizes; (void)n_in; (void)out_size; (void)ws_size;
  const float* ftq  = (const float*)d_in[0];
  const float* ftk  = (const float*)d_in[1];
  const int*   srcE = (const int*)d_in[2];
  const int*   dstE = (const int*)d_in[3];
  const float* Wq   = (const float*)d_in[4];
  const float* bq   = (const float*)d_in[5];
  const float* Wk   = (const float*)d_in[6];
  const float* Wv   = (const float*)d_in[7];
  const float* attn = (const float*)d_in[8];
  const float* gq   = (const float*)d_in[9];
  const float* bqn  = (const float*)d_in[10];
  const float* gk   = (const float*)d_in[11];
  const float* bkn  = (const float*)d_in[12];

  char* ws = (char*)d_ws;
  float* sums    = (float*)(ws + 0);             // 512 f     [0, 2048)  <- only memset
  int*   bscan   = (int*)(ws + 2048);            // 196 i     -> 2832
  int*   loc     = (int*)(ws + 4096);            // CPAD i    -> 204800
  int*   src_csr = (int*)(ws + 204800);          // 800000 i  -> 3404800
  unsigned short* rankE = (unsigned short*)(ws + 3404800);   // 800000 u16 -> 5004800
  unsigned short* hmat  = (unsigned short*)(ws + 5004800);   // 512*12544 u16 -> 17849856
  unsigned short* hbase = (unsigned short*)(ws + 17849856);  // 512*12544 u16 -> 30694912
  unsigned short* ctot  = (unsigned short*)(ws + 30694912);  // 512*49 u16 -> 30745088
  unsigned short* Wb    = (unsigned short*)(ws + 30745088);  // 3*16384 u16 -> 30843392
  float* biasf   = (float*)(ws + 30843392);      // 384 f -> 30844928
  unsigned short* xqb = (unsigned short*)(ws + 30844928);    // 50176*128 u16 -> 43689984
  unsigned short* qv  = (unsigned short*)(ws + 43689984);    // 50000*256 u16 -> 69289984
  unsigned short* kb  = (unsigned short*)(ws + 69289984);    // 50000*128 u16 -> 82089984
  float* out = (float*)d_out;

  hipMemsetAsync(ws, 0, 2048, stream);  // sums only

  hipLaunchKernelGGL(stats_hist_kernel, dim3(STAT_BLOCKS + HIST_BLOCKS), dim3(256), 0, stream,
                     ftq, ftk, sums, xqb, dstE, rankE, hmat, ctot);
  hipLaunchKernelGGL(colscan_fold_kernel, dim3(NCHUNK + 97), dim3(256), 0, stream,
                     hmat, hbase, loc, ctot, bscan,
                     Wq, bq, Wk, Wv, gq, bqn, gk, bkn, sums, Wb, biasf);
  hipLaunchKernelGGL(scatter_kernel, dim3(SCAT_BLOCKS), dim3(256), 0, stream,
                     dstE, srcE, loc, bscan, rankE, hbase, src_csr);
  hipLaunchKernelGGL(gemm_kernel, dim3(GEMM_BLOCKS), dim3(256), 0, stream,
                     xqb, ftk, Wb, biasf, qv, kb);
  hipLaunchKernelGGL(node_fused_kernel, dim3(NF_WAVES/4), dim3(256), 0, stream,
                     qv, kb, attn, src_csr, loc, bscan, out);
}

// Round 13
// 252.758 us; speedup vs baseline: 1.9055x; 1.0349x over previous
//
#include <hip/hip_runtime.h>

#define N_NODES 50000
#define N_EDGES 800000
#define FEATS 128
#define NCHUNK 196            // ceil(50000/256)
#define CPAD 50176            // NCHUNK*256 (loc padded)
#define GEMM_BX 196
#define GEMM_BLOCKS 392       // 196 qv-merged + 196 k
#define SCAT_BLOCKS 3125      // 3125*256 = 800000 exactly
#define NTILE 782             // ceil(50000/64)
#define NF_WAVES 8192
#define STAT_BLOCKS 512
#define HIST_BLOCKS 512       // 128 segments x 4 quarter-ranges
#define HSEG 128
#define ESEG 6250
#define HQ 12544              // bins per quarter (4*12544 = 50176 = CPAD)
#define CPQ 49                // chunks per quarter (12544/256)
#define NREP 8                // sums replicas (atomic contention split)

typedef __attribute__((ext_vector_type(8))) short bf16x8;
typedef __attribute__((ext_vector_type(4))) float f32x4;
typedef __attribute__((ext_vector_type(2))) float f32x2;
typedef __attribute__((ext_vector_type(4))) unsigned u32x4;   // native vec for nontemporal builtins
typedef union { uint4 u; bf16x8 v; } pack8;

__device__ __forceinline__ unsigned short f2bf(float f){
  unsigned u = __float_as_uint(f);
  u += 0x7FFF + ((u >> 16) & 1);           // RNE
  return (unsigned short)(u >> 16);
}
// HW packed f32->bf16 (RNE), 2 values / inst
__device__ __forceinline__ unsigned cvtpk(float lo, float hi){
  unsigned r;
  asm("v_cvt_pk_bf16_f32 %0, %1, %2" : "=v"(r) : "v"(lo), "v"(hi));
  return r;
}
// bf16 pair unpack, 1 VALU op per float
__device__ __forceinline__ void unpack8(uint4 p, float* f){
  f[0]=__uint_as_float(p.x << 16); f[1]=__uint_as_float(p.x & 0xffff0000u);
  f[2]=__uint_as_float(p.y << 16); f[3]=__uint_as_float(p.y & 0xffff0000u);
  f[4]=__uint_as_float(p.z << 16); f[5]=__uint_as_float(p.z & 0xffff0000u);
  f[6]=__uint_as_float(p.w << 16); f[7]=__uint_as_float(p.w & 0xffff0000u);
}
__device__ __forceinline__ void unpack8v(u32x4 p, float* f){
  f[0]=__uint_as_float(p.x << 16); f[1]=__uint_as_float(p.x & 0xffff0000u);
  f[2]=__uint_as_float(p.y << 16); f[3]=__uint_as_float(p.y & 0xffff0000u);
  f[4]=__uint_as_float(p.z << 16); f[5]=__uint_as_float(p.z & 0xffff0000u);
  f[6]=__uint_as_float(p.w << 16); f[7]=__uint_as_float(p.w & 0xffff0000u);
}

// ---------------- node 1: BN stats + bf16 q-emit (0..511) || quarter-hist + rank + ctot (512..1023)
__global__ __launch_bounds__(256) void stats_hist_kernel(
    const float* __restrict__ ftq, const float* __restrict__ ftk,
    float* __restrict__ sums8, unsigned short* __restrict__ xqb,
    const int* __restrict__ dstE, unsigned short* __restrict__ rankE,
    unsigned short* __restrict__ hmat, unsigned short* __restrict__ ctot){
  __shared__ float red[4*FEATS];               // 2 KB
  __shared__ unsigned lh[HQ/2];                // 12544 u16 bins packed -> 25088 B
  int tid = threadIdx.x, bid = blockIdx.x;
  if (bid < STAT_BLOCKS){
    for (int i = tid; i < 4*FEATS; i += 256) red[i] = 0.f;
    __syncthreads();
    int sub = tid >> 5, c4 = tid & 31;         // 32 lanes cover one 128-f row
    const float* Xs = (sub < 4) ? ftq : ftk;
    int so = (sub < 4) ? 0 : 2*FEATS;
    bool isq = (sub < 4);
    float a0=0,a1=0,a2=0,a3=0,b0=0,b1=0,b2=0,b3=0;
    #pragma unroll 4
    for (int r = bid*4 + (sub&3); r < N_NODES; r += STAT_BLOCKS*4){
      float4 x = *(const float4*)(Xs + (size_t)r*FEATS + c4*4);
      if (isq)  // bf16 A rows for qv GEMM plane (same RNE as GEMM-side cvt)
        *(uint2*)&xqb[(size_t)r*FEATS + c4*4] = make_uint2(cvtpk(x.x,x.y), cvtpk(x.z,x.w));
      a0+=x.x; b0+=x.x*x.x; a1+=x.y; b1+=x.y*x.y;
      a2+=x.z; b2+=x.z*x.z; a3+=x.w; b3+=x.w*x.w;
    }
    a0 += __shfl_xor(a0,32); a1 += __shfl_xor(a1,32);
    a2 += __shfl_xor(a2,32); a3 += __shfl_xor(a3,32);
    b0 += __shfl_xor(b0,32); b1 += __shfl_xor(b1,32);
    b2 += __shfl_xor(b2,32); b3 += __shfl_xor(b3,32);
    if ((tid & 63) < 32){
      int c0 = c4*4;
      atomicAdd(&red[so + c0+0], a0); atomicAdd(&red[so + c0+1], a1);
      atomicAdd(&red[so + c0+2], a2); atomicAdd(&red[so + c0+3], a3);
      atomicAdd(&red[so + FEATS + c0+0], b0); atomicAdd(&red[so + FEATS + c0+1], b1);
      atomicAdd(&red[so + FEATS + c0+2], b2); atomicAdd(&red[so + FEATS + c0+3], b3);
    }
    __syncthreads();
    float* srep = sums8 + (bid & (NREP-1))*512;   // 8-way replica: 8x less addr contention
    for (int i = tid; i < 4*FEATS; i += 256) atomicAdd(&srep[i], red[i]);
  } else {
    int hb = bid - STAT_BLOCKS;                // 0..511
    int seg = hb >> 2, q = hb & 3;
    int dlo = q * HQ;
    for (int i = tid; i < HQ/2; i += 256) lh[i] = 0;
    __syncthreads();
    int e0 = seg * ESEG;
    for (int t = e0 + tid; t < e0 + ESEG; t += 256){
      int d = dstE[t] - dlo;
      if ((unsigned)d < (unsigned)HQ){
        unsigned sh = (d & 1) * 16;
        unsigned old = atomicAdd(&lh[d >> 1], 1u << sh);
        rankE[t] = (unsigned short)((old >> sh) & 0xffffu);   // local rank in (seg,d)
      }
    }
    __syncthreads();
    unsigned* row = (unsigned*)(hmat + (size_t)hb * HQ);
    for (int i = tid; i < HQ/2; i += 256) row[i] = lh[i];
    // per-chunk totals -> ctot (plain stores, no atomics)
    int wv = tid >> 6, ln = tid & 63;
    for (int c = wv; c < CPQ; c += 4){
      unsigned w0 = lh[c*128 + ln];
      unsigned w1 = lh[c*128 + 64 + ln];
      unsigned t = (w0 & 0xffffu) + (w0 >> 16) + (w1 & 0xffffu) + (w1 >> 16);
      #pragma unroll
      for (int o = 1; o < 64; o <<= 1) t += __shfl_xor((int)t, o);
      if (ln == 0) ctot[hb*CPQ + c] = (unsigned short)t;   // total <= 6250 fits u16
    }
  }
}

// ---------------- node 2: colscan + chunk scan (0..195) || BN-fold (196..291) || bscan (292)
__global__ __launch_bounds__(256) void colscan_fold_kernel(
    const unsigned short* __restrict__ hmat, unsigned short* __restrict__ hbase,
    int* __restrict__ loc, const unsigned short* __restrict__ ctot, int* __restrict__ bscan,
    const float* __restrict__ Wq, const float* __restrict__ bq,
    const float* __restrict__ Wk, const float* __restrict__ Wv,
    const float* __restrict__ gq, const float* __restrict__ bqn,
    const float* __restrict__ gk, const float* __restrict__ bkn,
    const float* __restrict__ sums8,
    unsigned short* __restrict__ Wb, float* __restrict__ bias){
  __shared__ int s[256];
  int tid = threadIdx.x, bid = blockIdx.x;
  if (bid < NCHUNK){
    int q = bid / CPQ;                         // chunks never straddle quarters (49*256=12544)
    int d = bid*256 + tid;
    int col = d - q*HQ;
    const unsigned short* hp = hmat + (size_t)q*HQ + col;   // row hb = seg*4+q
    unsigned short* bp = hbase + (size_t)q*HQ + col;
    int run = 0;
    #pragma unroll 8
    for (int sg = 0; sg < HSEG; sg++){
      int v = hp[(size_t)sg*4*HQ];
      bp[(size_t)sg*4*HQ] = (unsigned short)run;   // exclusive prefix over segments
      run += v;
    }
    s[tid] = run; __syncthreads();
    for (int dd = 1; dd < 256; dd <<= 1){
      int tv = (tid >= dd) ? s[tid-dd] : 0; __syncthreads();
      s[tid] += tv; __syncthreads();
    }
    loc[d] = s[tid] - run;                     // chunk-local exclusive
  } else if (bid == NCHUNK + 96){              // bscan block: reduce ctot, ladder-scan
    int v = 0;
    if (tid < NCHUNK){
      int q = tid / CPQ, cc = tid - q*CPQ;
      const unsigned short* cp = ctot + q*CPQ + cc;   // row hb = seg*4+q
      #pragma unroll 8
      for (int sg = 0; sg < HSEG; sg++) v += cp[(size_t)sg*4*CPQ];
    }
    s[tid] = v; __syncthreads();
    for (int dd = 1; dd < 256; dd <<= 1){
      int tv = (tid >= dd) ? s[tid-dd] : 0; __syncthreads();
      s[tid] += tv; __syncthreads();
    }
    if (tid < NCHUNK) bscan[tid] = s[tid] - v;
  } else {
    int wv = (bid - NCHUNK)*4 + (tid >> 6);    // 0..383
    int lane = tid & 63;
    int m = wv >> 7;                           // 0=q,1=v,2=k
    int o = wv & 127;
    const float* Wsrc = (m==0) ? Wq : (m==1) ? Wv : Wk;
    const float* g   = (m==2) ? gk : gq;
    const float* bb  = (m==2) ? bkn : bqn;
    int off = (m==2) ? 2*FEATS : 0;
    const float invN = 1.0f / (float)N_NODES;
    float acc = 0.f;
    unsigned short w2[2];
    int i0 = lane*2;
    #pragma unroll
    for (int t = 0; t < 2; t++){
      int i = i0 + t;
      float sm = 0.f, sv = 0.f;                // reduce 8 replicas (L2-hot, 16 loads)
      #pragma unroll
      for (int r = 0; r < NREP; r++){
        sm += sums8[r*512 + off + i];
        sv += sums8[r*512 + off + FEATS + i];
      }
      float mean = sm*invN;
      float var  = sv*invN - mean*mean;
      float rstd = rsqrtf(var + 1e-5f);
      float scale = g[i]*rstd;
      float shift = bb[i] - mean*scale;
      float w = Wsrc[o*FEATS + i];
      w2[t] = f2bf(w*scale);
      acc += shift*w;
    }
    ((unsigned*)Wb)[(m*FEATS*FEATS + o*FEATS + i0) >> 1] =
        (unsigned)w2[0] | ((unsigned)w2[1] << 16);
    #pragma unroll
    for (int off2 = 1; off2 < 64; off2 <<= 1) acc += __shfl_xor(acc, off2);
    if (lane == 0) bias[m*FEATS + o] = acc + ((m==0) ? bq[o] : 0.f);
  }
}

// ---------------- node 3: fully atomic-free CSR scatter (no LDS, tiny VGPR -> full occupancy)
__global__ __launch_bounds__(256) void scatter_kernel(
    const int* __restrict__ dstE, const int* __restrict__ srcE,
    const int* __restrict__ loc, const int* __restrict__ bscan,
    const unsigned short* __restrict__ rankE, const unsigned short* __restrict__ hbase,
    int* __restrict__ src_csr){
  int t = blockIdx.x*256 + threadIdx.x;        // exactly covers N_EDGES
  int d = dstE[t];
  int seg = t / ESEG;
  int q = d / HQ;
  int base = (int)hbase[(size_t)(seg*4 + q)*HQ + (d - q*HQ)];
  src_csr[loc[d] + bscan[d >> 8] + base + (int)rankE[t]] = srcE[t];
}

// ---------------- node 4: merged-plane GEMM
// blocks 0..195:  A=xqb (bf16, no convert), B = {Wq, Wv} both staged -> q and v outputs
// blocks 196..391: A=ftk (f32 + cvtpk),     B = {Wk}                 -> k output
__global__ __launch_bounds__(256) void gemm_kernel(
    const unsigned short* __restrict__ xqb, const float* __restrict__ ftk,
    const unsigned short* __restrict__ Wball, const float* __restrict__ biasall,
    unsigned short* __restrict__ qv, unsigned short* __restrict__ kb){
  __shared__ unsigned short Bs[2][FEATS][FEATS];   // 64KB, XOR-swizzled 16B chunks
  int tid = threadIdx.x, bid = blockIdx.x;
  int isk = (bid >= GEMM_BX);
  int bx = isk ? bid - GEMM_BX : bid;
  int nplanes = isk ? 1 : 2;
  { // stage B plane(s) with chunk-XOR swizzle: chunk' = chunk ^ (row&15)
    for (int p = 0; p < nplanes; p++){
      int m = isk ? 2 : p;
      const uint4* srcp = (const uint4*)(Wball + m*FEATS*FEATS);
      for (int idx = tid; idx < FEATS*FEATS/8; idx += 256){
        int n = idx >> 4, ck = idx & 15;
        *(uint4*)&Bs[p][n][(ck ^ (n & 15))*8] = srcp[idx];
      }
    }
  }
  __syncthreads();                              // only barrier in the kernel
  int wave = tid >> 6, lane = tid & 63;
  int mrow = lane & 15, quad = lane >> 4;
  float bv[2][8];
  #pragma unroll
  for (int p = 0; p < 2; p++)
    #pragma unroll
    for (int ct = 0; ct < 8; ct++)
      bv[p][ct] = biasall[(isk ? 2 : p)*FEATS + ct*16 + mrow];
  uint4 cur[4], nxt[4];
  auto loadA = [&](uint4* buf, int t){
    int arow = t*64 + wave*16 + mrow;
    if (!isk){
      const unsigned short* xp = xqb + (size_t)arow*FEATS + quad*8;  // padded rows
      buf[0] = *(const uint4*)xp;
      buf[1] = *(const uint4*)(xp + 32);
      buf[2] = *(const uint4*)(xp + 64);
      buf[3] = *(const uint4*)(xp + 96);
    } else {
      bool rok = arow < N_NODES;
      const float* xp = ftk + (size_t)(rok ? arow : 0)*FEATS + quad*8;
      #pragma unroll
      for (int kt = 0; kt < 4; kt++){
        float4 x0 = *(const float4*)(xp + kt*32);
        float4 x1 = *(const float4*)(xp + kt*32 + 4);
        if (!rok){ x0 = make_float4(0.f,0.f,0.f,0.f); x1 = x0; }
        buf[kt].x = cvtpk(x0.x, x0.y); buf[kt].y = cvtpk(x0.z, x0.w);
        buf[kt].z = cvtpk(x1.x, x1.y); buf[kt].w = cvtpk(x1.z, x1.w);
      }
    }
  };
  loadA(cur, bx);
  for (int t = bx; t < NTILE; t += GEMM_BX){
    int tn = t + GEMM_BX;
    if (tn < NTILE) loadA(nxt, tn);             // prefetch next A tile under MFMA
    f32x4 acc[2][8];
    #pragma unroll
    for (int p = 0; p < 2; p++)
      #pragma unroll
      for (int i = 0; i < 8; i++) acc[p][i] = (f32x4){0.f,0.f,0.f,0.f};
    #pragma unroll
    for (int kt = 0; kt < 4; kt++){
      pack8 a; a.u = cur[kt];
      #pragma unroll
      for (int ct = 0; ct < 8; ct++){
        bf16x8 b0 = *(bf16x8*)&Bs[0][ct*16 + mrow][((kt*4 + quad) ^ mrow)*8];
        acc[0][ct] = __builtin_amdgcn_mfma_f32_16x16x32_bf16(a.v, b0, acc[0][ct], 0, 0, 0);
      }
      if (!isk){
        #pragma unroll
        for (int ct = 0; ct < 8; ct++){
          bf16x8 b1 = *(bf16x8*)&Bs[1][ct*16 + mrow][((kt*4 + quad) ^ mrow)*8];
          acc[1][ct] = __builtin_amdgcn_mfma_f32_16x16x32_bf16(a.v, b1, acc[1][ct], 0, 0, 0);
        }
      }
    }
    int row0 = t*64;
    #pragma unroll
    for (int p = 0; p < 2; p++){
      if (isk && p) break;
      unsigned short* Out = isk ? kb : (qv + p*128);
      const int ostride = isk ? FEATS : 256;
      #pragma unroll
      for (int ct = 0; ct < 8; ct++){
        int col = ct*16 + mrow;
        #pragma unroll
        for (int v = 0; v < 4; v++){
          int orow = row0 + wave*16 + quad*4 + v;
          float sv = acc[p][ct][v] + bv[p][ct];
          float pf = __shfl_xor(sv, 1);         // partner col's f32 sum
          if (!(mrow & 1) && orow < N_NODES)
            *(unsigned*)&Out[(size_t)orow*ostride + col] = cvtpk(sv, pf);
        }
      }
    }
    #pragma unroll
    for (int i = 0; i < 4; i++) cur[i] = nxt[i];
  }
}

// ---------------- node 5: per-dst-node scores + max-free softmax agg (static interleave)
// nt-hints: kb rows (read once/node) and out (write once) bypass L2 -> keep qv resident
__global__ __launch_bounds__(256) void node_fused_kernel(
    const unsigned short* __restrict__ qv, const unsigned short* __restrict__ kb,
    const float* __restrict__ attn, const int* __restrict__ src_csr,
    const int* __restrict__ loc, const int* __restrict__ bscan,
    float* __restrict__ out){
  int tid = threadIdx.x;
  int lane = tid & 63;
  int h = lane & 7, g = lane >> 3;
  int w = blockIdx.x*4 + (tid >> 6);
  const float L2E = 1.44269504f;
  float ar[16];
  {
    const uint4* ap = (const uint4*)(attn + h*16);
    uint4 a0 = ap[0], a1 = ap[1], a2 = ap[2], a3 = ap[3];
    ar[0]=__uint_as_float(a0.x); ar[1]=__uint_as_float(a0.y); ar[2]=__uint_as_float(a0.z); ar[3]=__uint_as_float(a0.w);
    ar[4]=__uint_as_float(a1.x); ar[5]=__uint_as_float(a1.y); ar[6]=__uint_as_float(a1.z); ar[7]=__uint_as_float(a1.w);
    ar[8]=__uint_as_float(a2.x); ar[9]=__uint_as_float(a2.y); ar[10]=__uint_as_float(a2.z); ar[11]=__uint_as_float(a2.w);
    ar[12]=__uint_as_float(a3.x); ar[13]=__uint_as_float(a3.y); ar[14]=__uint_as_float(a3.z); ar[15]=__uint_as_float(a3.w);
  }
  for (int n = w; n < N_NODES; n += NF_WAVES){
    int off0 = loc[n]   + bscan[n>>8];
    int off1 = loc[n+1] + bscan[(n+1)>>8];      // loc[50000] valid (padded chunk 195)
    int deg = off1 - off0;
    if (deg == 0){
      f32x2 z = (f32x2){0.f, 0.f};
      __builtin_nontemporal_store(z, (f32x2*)(out + (size_t)n*FEATS) + lane);
      continue;
    }
    float kf2[16];
    {
      const unsigned short* kr = kb + (size_t)n*FEATS + h*16;
      u32x4 k0 = __builtin_nontemporal_load((const u32x4*)kr);
      u32x4 k1 = __builtin_nontemporal_load((const u32x4*)kr + 1);
      float kf[16]; unpack8v(k0, kf); unpack8v(k1, kf+8);
      #pragma unroll
      for (int i = 0; i < 16; i++) kf2[i] = -L2E * kf[i];
    }
    float ssum = 0.f;
    float acc[16];
    #pragma unroll
    for (int i = 0; i < 16; i++) acc[i] = 0.f;
    if (g < deg){
      int sA = src_csr[off0 + g];
      int jB = g + 8;
      int sB = (jB < deg) ? src_csr[off0 + jB] : sA;   // dup tail -> L1 hit
      const unsigned short* pA = qv + (size_t)sA*256 + h*16;
      uint4 qa0 = *(const uint4*)pA;
      uint4 qa1 = *(const uint4*)(pA + 8);
      while (true){
        uint4 va0 = *(const uint4*)(pA + 128);   // current v (interleaved row)
        uint4 va1 = *(const uint4*)(pA + 136);
        const unsigned short* pB = qv + (size_t)sB*256 + h*16;
        uint4 qb0 = *(const uint4*)pB;           // next q prefetch
        uint4 qb1 = *(const uint4*)(pB + 8);
        int jC = jB + 8;
        int sC = (jC < deg) ? src_csr[off0 + jC] : sB;
        float qf[16]; unpack8(qa0, qf); unpack8(qa1, qf+8);
        float ta = 0.f, tb = 0.f, tc = 0.f, td = 0.f;
        #pragma unroll
        for (int i = 0; i < 16; i += 4){
          float x0 = fmaf(qf[i+0], -L2E, kf2[i+0]);
          float x1 = fmaf(qf[i+1], -L2E, kf2[i+1]);
          float x2 = fmaf(qf[i+2], -L2E, kf2[i+2]);
          float x3 = fmaf(qf[i+3], -L2E, kf2[i+3]);
          ta = fmaf(ar[i+0], __builtin_amdgcn_rcpf(1.f + __builtin_amdgcn_exp2f(x0)), ta);
          tb = fmaf(ar[i+1], __builtin_amdgcn_rcpf(1.f + __builtin_amdgcn_exp2f(x1)), tb);
          tc = fmaf(ar[i+2], __builtin_amdgcn_rcpf(1.f + __builtin_amdgcn_exp2f(x2)), tc);
          td = fmaf(ar[i+3], __builtin_amdgcn_rcpf(1.f + __builtin_amdgcn_exp2f(x3)), td);
        }
        float t = (ta + tb) + (tc + td);
        float ex = __builtin_amdgcn_exp2f(t * L2E);   // |t|<=sum|attn| -> max-free safe
        ssum += ex;
        float vf[16]; unpack8(va0, vf); unpack8(va1, vf+8);
        #pragma unroll
        for (int i = 0; i < 16; i++) acc[i] = fmaf(ex, vf[i], acc[i]);
        if (jB >= deg) break;
        qa0 = qb0; qa1 = qb1; pA = pB;
        jB = jC; sB = sC;
      }
    }
    ssum += __shfl_xor(ssum, 8); ssum += __shfl_xor(ssum, 16); ssum += __shfl_xor(ssum, 32);
    #pragma unroll
    for (int i = 0; i < 16; i++){
      acc[i] += __shfl_xor(acc[i], 8);
      acc[i] += __shfl_xor(acc[i], 16);
      acc[i] += __shfl_xor(acc[i], 32);
    }
    if (g == 0){
      float inv_s = 1.f / ssum;
      f32x4* op = (f32x4*)(out + (size_t)n*FEATS + h*16);
      __builtin_nontemporal_store((f32x4){acc[0]*inv_s, acc[1]*inv_s, acc[2]*inv_s, acc[3]*inv_s}, op);
      __builtin_nontemporal_store((f32x4){acc[4]*inv_s, acc[5]*inv_s, acc[6]*inv_s, acc[7]*inv_s}, op+1);
      __builtin_nontemporal_store((f32x4){acc[8]*inv_s, acc[9]*inv_s, acc[10]*inv_s, acc[11]*inv_s}, op+2);
      __builtin_nontemporal_store((f32x4){acc[12]*inv_s, acc[13]*inv_s, acc[14]*inv_s, acc[15]*inv_s}, op+3);
    }
  }
}

extern "C" void kernel_launch(void* const* d_in, const int* in_sizes, int n_in,
                              void* d_out, int out_size, void* d_ws, size_t ws_size,
                              hipStream_t stream){
  (void)in_sizes; (void)n_in; (void)out_size; (void)ws_size;
  const float* ftq  = (const float*)d_in[0];
  const float* ftk  = (const float*)d_in[1];
  const int*   srcE = (const int*)d_in[2];
  const int*   dstE = (const int*)d_in[3];
  const float* Wq   = (const float*)d_in[4];
  const float* bq   = (const float*)d_in[5];
  const float* Wk   = (const float*)d_in[6];
  const float* Wv   = (const float*)d_in[7];
  const float* attn = (const float*)d_in[8];
  const float* gq   = (const float*)d_in[9];
  const float* bqn  = (const float*)d_in[10];
  const float* gk   = (const float*)d_in[11];
  const float* bkn  = (const float*)d_in[12];

  char* ws = (char*)d_ws;
  float* sums8   = (float*)(ws + 0);             // 8*512 f   [0, 16384)  <- only memset
  int*   bscan   = (int*)(ws + 16384);           // 196 i     -> 17168
  int*   loc     = (int*)(ws + 17408);           // CPAD i    -> 218112
  int*   src_csr = (int*)(ws + 218112);          // 800000 i  -> 3418112
  unsigned short* rankE = (unsigned short*)(ws + 3418112);   // 800000 u16 -> 5018112
  unsigned short* hmat  = (unsigned short*)(ws + 5018112);   // 512*12544 u16 -> 17863168
  unsigned short* hbase = (unsigned short*)(ws + 17863168);  // 512*12544 u16 -> 30708224
  unsigned short* ctot  = (unsigned short*)(ws + 30708224);  // 512*49 u16 -> 30758400
  unsigned short* Wb    = (unsigned short*)(ws + 30758400);  // 3*16384 u16 -> 30856704
  float* biasf   = (float*)(ws + 30856704);      // 384 f -> 30858240
  unsigned short* xqb = (unsigned short*)(ws + 30858240);    // 50176*128 u16 -> 43703296
  unsigned short* qv  = (unsigned short*)(ws + 43703296);    // 50000*256 u16 -> 69303296
  unsigned short* kb  = (unsigned short*)(ws + 69303296);    // 50000*128 u16 -> 82103296
  float* out = (float*)d_out;

  hipMemsetAsync(ws, 0, 16384, stream);  // sums8 only

  hipLaunchKernelGGL(stats_hist_kernel, dim3(STAT_BLOCKS + HIST_BLOCKS), dim3(256), 0, stream,
                     ftq, ftk, sums8, xqb, dstE, rankE, hmat, ctot);
  hipLaunchKernelGGL(colscan_fold_kernel, dim3(NCHUNK + 97), dim3(256), 0, stream,
                     hmat, hbase, loc, ctot, bscan,
                     Wq, bq, Wk, Wv, gq, bqn, gk, bkn, sums8, Wb, biasf);
  hipLaunchKernelGGL(scatter_kernel, dim3(SCAT_BLOCKS), dim3(256), 0, stream,
                     dstE, srcE, loc, bscan, rankE, hbase, src_csr);
  hipLaunchKernelGGL(gemm_kernel, dim3(GEMM_BLOCKS), dim3(256), 0, stream,
                     xqb, ftk, Wb, biasf, qv, kb);
  hipLaunchKernelGGL(node_fused_kernel, dim3(NF_WAVES/4), dim3(256), 0, stream,
                     qv, kb, attn, src_csr, loc, bscan, out);
}